// Round 1
// baseline (7895.085 us; speedup 1.0000x reference)
//
#include <hip/hip_runtime.h>

// ============================================================================
// HWNet-SPP forward pass, fp32 correctness-first implementation.
// Pipeline: edge-pad -> [conv -> BN-stats -> BN+ReLU(+pool)] x5 -> ROI-SPP
//           -> FC1 -> BN1d+ReLU -> concat(phoc) -> FC2 -> BN1d+ReLU
// Conv biases are skipped: BN subtracts the per-channel mean over the same
// axes the bias is constant on, so they cancel exactly.
// ============================================================================

#define THREADS 256

// ---------------- pad (edge mode, 2 on each H/W side) ----------------
__global__ __launch_bounds__(THREADS) void pad_edge_k(const float* __restrict__ x,
                                                      float* __restrict__ p) {
  int i = blockIdx.x * THREADS + threadIdx.x;
  const int TOT = 64 * 52 * 132;
  if (i >= TOT) return;
  int w = i % 132; int t = i / 132; int h = t % 52; int n = t / 52;
  int sh = h - 2; sh = sh < 0 ? 0 : (sh > 47 ? 47 : sh);
  int sw = w - 2; sw = sw < 0 ? 0 : (sw > 127 ? 127 : sw);
  p[i] = x[(n * 48 + sh) * 128 + sw];
}

// ---------------- direct convolution (cross-correlation, NCHW/OIHW) --------
// One thread per output pixel, COPT output channels per thread.
// co0 comes from blockIdx.y -> weight reads are wave-uniform (scalar loads).
template<int CIN,int COUT,int IH,int IW,int OH,int OW,int KS,int PAD,int COPT>
__global__ __launch_bounds__(THREADS) void conv2d_k(const float* __restrict__ in,
                                                    const float* __restrict__ wt,
                                                    float* __restrict__ out, int N) {
  int idx = blockIdx.x * THREADS + threadIdx.x;
  int total = N * OH * OW;
  if (idx >= total) return;
  int n  = idx / (OH * OW);
  int hw = idx % (OH * OW);
  int h = hw / OW, w = hw % OW;
  int co0 = blockIdx.y * COPT;
  float acc[COPT];
#pragma unroll
  for (int j = 0; j < COPT; j++) acc[j] = 0.f;
  const int KK = KS * KS;
  for (int ci = 0; ci < CIN; ci++) {
    const float* ip = in + ((size_t)(n * CIN) + ci) * (IH * IW);
    const float* wp = wt + ((size_t)co0 * CIN + ci) * KK;
#pragma unroll
    for (int kh = 0; kh < KS; kh++) {
      int ih = h + kh - PAD;
      if (ih < 0 || ih >= IH) continue;
      const float* rp = ip + ih * IW;
#pragma unroll
      for (int kw = 0; kw < KS; kw++) {
        int iw = w + kw - PAD;
        if (iw < 0 || iw >= IW) continue;
        float v = rp[iw];
#pragma unroll
        for (int j = 0; j < COPT; j++)
          acc[j] += v * wp[(size_t)j * CIN * KK + kh * KS + kw];
      }
    }
  }
#pragma unroll
  for (int j = 0; j < COPT; j++)
    out[(((size_t)n * COUT + co0 + j) * OH + h) * OW + w] = acc[j];
}

// ---------------- BN2d stats: partial sums (deterministic, no atomics) -----
// grid (C, S); block s handles n in [s*N/S, (s+1)*N/S)
__global__ __launch_bounds__(THREADS) void bn2d_stats_partial(const float* __restrict__ x,
                                                              float* __restrict__ part,
                                                              int N, int C, int HW, int S) {
  int c = blockIdx.x, s = blockIdx.y;
  int nper = N / S;
  int n0 = s * nper, n1 = n0 + nper;
  float sum = 0.f, sq = 0.f;
  for (int n = n0; n < n1; n++) {
    const float* p = x + ((size_t)n * C + c) * HW;
    for (int i = threadIdx.x; i < HW; i += THREADS) {
      float v = p[i]; sum += v; sq += v * v;
    }
  }
  __shared__ float ls[THREADS], lq[THREADS];
  ls[threadIdx.x] = sum; lq[threadIdx.x] = sq;
  __syncthreads();
  for (int o = THREADS / 2; o > 0; o >>= 1) {
    if (threadIdx.x < o) { ls[threadIdx.x] += ls[threadIdx.x + o]; lq[threadIdx.x] += lq[threadIdx.x + o]; }
    __syncthreads();
  }
  if (threadIdx.x == 0) {
    part[(c * S + s) * 2 + 0] = ls[0];
    part[(c * S + s) * 2 + 1] = lq[0];
  }
}

__global__ void bn2d_finalize(const float* __restrict__ part,
                              const float* __restrict__ g, const float* __restrict__ b,
                              float* __restrict__ scale, float* __restrict__ shift,
                              int C, int S, float invCount) {
  int c = blockIdx.x * blockDim.x + threadIdx.x;
  if (c >= C) return;
  float sum = 0.f, sq = 0.f;
  for (int s = 0; s < S; s++) { sum += part[(c * S + s) * 2]; sq += part[(c * S + s) * 2 + 1]; }
  float m = sum * invCount;
  float var = sq * invCount - m * m;
  float sc = g[c] * rsqrtf(var + 1e-5f);
  scale[c] = sc;
  shift[c] = b[c] - m * sc;
}

// ---------------- fused BN + ReLU + 2x2 maxpool ----------------
__global__ __launch_bounds__(THREADS) void bn_relu_pool_k(const float* __restrict__ x,
                                                          float* __restrict__ y,
                                                          const float* __restrict__ scale,
                                                          const float* __restrict__ shift,
                                                          int N, int C, int H, int W) {
  int OH = H / 2, OW = W / 2;
  int total = N * C * OH * OW;
  int i = blockIdx.x * THREADS + threadIdx.x;
  if (i >= total) return;
  int ow = i % OW; int t = i / OW; int oh = t % OH; t /= OH; int c = t % C; int n = t / C;
  const float* p = x + (((size_t)n * C + c) * H + oh * 2) * W + ow * 2;
  float sc = scale[c], sh = shift[c];
  float a = p[0] * sc + sh;
  float b = p[1] * sc + sh;
  float e = p[W] * sc + sh;
  float d = p[W + 1] * sc + sh;
  float m = fmaxf(fmaxf(a, b), fmaxf(e, d));
  y[i] = fmaxf(m, 0.f);
}

// ---------------- fused BN + ReLU in-place ----------------
__global__ __launch_bounds__(THREADS) void bn_relu_inplace_k(float* __restrict__ x,
                                                             const float* __restrict__ scale,
                                                             const float* __restrict__ shift,
                                                             int total, int C, int HW) {
  int i = blockIdx.x * THREADS + threadIdx.x;
  if (i >= total) return;
  int c = (i / HW) % C;
  x[i] = fmaxf(x[i] * scale[c] + shift[c], 0.f);
}

// ---------------- ROI SPP (levels 1..3, feat 64x512x6x16) ----------------
__global__ __launch_bounds__(THREADS) void spp_k(const float* __restrict__ feat,
                                                 const int* __restrict__ roi,
                                                 float* __restrict__ out) {
  int c = blockIdx.x * THREADS + threadIdx.x;  // channel 0..511 (grid.x == 2)
  int r = blockIdx.y;                          // roi 0..255
  const int* rp = roi + r * 5;
  int im = rp[0];
  int c1 = rp[1] >> 3, r1 = rp[2] >> 3, c2 = rp[3] >> 3, r2 = rp[4] >> 3;
  int w = c2 - c1 + 1;
  int lo[6], hi[6];
  int bi = 0;
#pragma unroll
  for (int l = 1; l <= 3; l++)
    for (int k = 0; k < l; k++) {
      lo[bi] = c1 + (k * w) / l;
      hi[bi] = c1 + ((k + 1) * w + l - 1) / l - 1;
      bi++;
    }
  float mx[6];
#pragma unroll
  for (int b = 0; b < 6; b++) mx[b] = -1e30f;
  const float* fp = feat + ((size_t)im * 512 + c) * 96;
  for (int row = r1; row <= r2; row++) {
    for (int col = c1; col <= c2; col++) {
      float v = fp[row * 16 + col];
#pragma unroll
      for (int b = 0; b < 6; b++)
        if (col >= lo[b] && col <= hi[b]) mx[b] = fmaxf(mx[b], v);
    }
  }
  float* op = out + (size_t)r * 3072;
  op[c]                 = mx[0];
  op[512  + c * 2 + 0]  = mx[1];
  op[512  + c * 2 + 1]  = mx[2];
  op[1536 + c * 3 + 0]  = mx[3];
  op[1536 + c * 3 + 1]  = mx[4];
  op[1536 + c * 3 + 2]  = mx[5];
}

// ---------------- GEMM: C[m,n] = sum_k A[m,k]*B[n,k] + bias[n] -------------
// 64x64 tile, BK=16, 256 threads, 4x4 register tile per thread.
// M, N assumed multiples of 64; K arbitrary (tail zero-filled).
__global__ __launch_bounds__(THREADS) void gemm_bias_k(const float* __restrict__ A,
                                                       const float* __restrict__ B,
                                                       const float* __restrict__ bias,
                                                       float* __restrict__ Cc,
                                                       int M, int Nn, int K, int lda, int ldb) {
  __shared__ float As[16][68];
  __shared__ float Bs[16][68];
  int m0 = blockIdx.y * 64, n0 = blockIdx.x * 64;
  int t = threadIdx.x;
  int tx = t & 15, ty = t >> 4;
  int lk = t & 15, lr = t >> 4;
  float acc[4][4] = {{0.f}};
  for (int k0 = 0; k0 < K; k0 += 16) {
    int gk = k0 + lk;
    bool kin = gk < K;
#pragma unroll
    for (int j = 0; j < 4; j++) {
      int row = lr * 4 + j;
      As[lk][row] = kin ? A[(size_t)(m0 + row) * lda + gk] : 0.f;
      Bs[lk][row] = kin ? B[(size_t)(n0 + row) * ldb + gk] : 0.f;
    }
    __syncthreads();
#pragma unroll
    for (int kk = 0; kk < 16; kk++) {
      float a[4], bb[4];
#pragma unroll
      for (int i = 0; i < 4; i++) a[i] = As[kk][ty * 4 + i];
#pragma unroll
      for (int j = 0; j < 4; j++) bb[j] = Bs[kk][tx * 4 + j];
#pragma unroll
      for (int i = 0; i < 4; i++)
#pragma unroll
        for (int j = 0; j < 4; j++)
          acc[i][j] += a[i] * bb[j];
    }
    __syncthreads();
  }
#pragma unroll
  for (int i = 0; i < 4; i++) {
    int m = m0 + ty * 4 + i;
#pragma unroll
    for (int j = 0; j < 4; j++) {
      int n = n0 + tx * 4 + j;
      Cc[(size_t)m * Nn + n] = acc[i][j] + bias[n];
    }
  }
}

// ---------------- BN1d stats (per-feature over rows) ----------------
__global__ void bn1d_stats_k(const float* __restrict__ x,
                             const float* __restrict__ g, const float* __restrict__ b,
                             float* __restrict__ scale, float* __restrict__ shift,
                             int R, int F) {
  int f = blockIdx.x * blockDim.x + threadIdx.x;
  if (f >= F) return;
  float sum = 0.f, sq = 0.f;
  for (int r = 0; r < R; r++) {
    float v = x[(size_t)r * F + f];
    sum += v; sq += v * v;
  }
  float invR = 1.f / (float)R;
  float m = sum * invR;
  float var = sq * invR - m * m;
  float sc = g[f] * rsqrtf(var + 1e-5f);
  scale[f] = sc;
  shift[f] = b[f] - m * sc;
}

__global__ __launch_bounds__(THREADS) void bn1d_apply_relu_k(float* __restrict__ x,
                                                             const float* __restrict__ scale,
                                                             const float* __restrict__ shift,
                                                             int total, int F) {
  int i = blockIdx.x * THREADS + threadIdx.x;
  if (i >= total) return;
  int f = i % F;
  x[i] = fmaxf(x[i] * scale[f] + shift[f], 0.f);
}

// ---------------- concat [fc1relu (256,2048) | phoc (256,5853)] ------------
__global__ __launch_bounds__(THREADS) void concat_k(const float* __restrict__ a,
                                                    const float* __restrict__ b,
                                                    float* __restrict__ o) {
  int i = blockIdx.x * THREADS + threadIdx.x;
  const int TOT = 256 * 7901;
  if (i >= TOT) return;
  int col = i % 7901; int r = i / 7901;
  o[i] = (col < 2048) ? a[r * 2048 + col] : b[(size_t)r * 5853 + (col - 2048)];
}

// ============================================================================
extern "C" void kernel_launch(void* const* d_in, const int* in_sizes, int n_in,
                              void* d_out, int out_size, void* d_ws, size_t ws_size,
                              hipStream_t stream) {
  (void)in_sizes; (void)n_in; (void)out_size; (void)ws_size;

  const float* x    = (const float*)d_in[0];
  const int*   roi  = (const int*)  d_in[1];
  const float* phoc = (const float*)d_in[2];
  const float* c1w  = (const float*)d_in[3];
  const float* g1   = (const float*)d_in[5];
  const float* b1   = (const float*)d_in[6];
  const float* c2w  = (const float*)d_in[7];
  const float* g2   = (const float*)d_in[9];
  const float* b2   = (const float*)d_in[10];
  const float* c3w  = (const float*)d_in[11];
  const float* g3   = (const float*)d_in[13];
  const float* b3   = (const float*)d_in[14];
  const float* c4w  = (const float*)d_in[15];
  const float* g4   = (const float*)d_in[17];
  const float* b4   = (const float*)d_in[18];
  const float* c5w  = (const float*)d_in[19];
  const float* g5   = (const float*)d_in[21];
  const float* b5   = (const float*)d_in[22];
  const float* f1w  = (const float*)d_in[23];
  const float* f1b  = (const float*)d_in[24];
  const float* g6   = (const float*)d_in[25];
  const float* b6   = (const float*)d_in[26];
  const float* f2w  = (const float*)d_in[27];
  const float* f2b  = (const float*)d_in[28];
  const float* g7   = (const float*)d_in[29];
  const float* b7   = (const float*)d_in[30];
  float* out = (float*)d_out;

  // ---- workspace layout (~172 MB) ----
  char* ws = (char*)d_ws;
  float* P    = (float*)(ws + 0x0);         // 64*52*132      = 1.76 MB
  float* T    = (float*)(ws + 0x200000);    // up to 100.66 MB (conv1 out)
  float* U    = (float*)(ws + 0x6400000);   // up to 50.33 MB (conv2/conv4 out)
  float* S    = (float*)(ws + 0x9500000);   // spp 256x3072  = 3.15 MB
  float* F1   = (float*)(ws + 0x9900000);   // fc1 256x2048  = 2 MB
  float* CC   = (float*)(ws + 0x9B00000);   // concat 256x7901 = 8.09 MB
  float* PART = (float*)(ws + 0xA400000);   // bn partials (<=512*8*2 floats)
  float* SC   = (float*)(ws + 0xA410000);   // scale (<=2048)
  float* SH   = (float*)(ws + 0xA414000);   // shift (<=2048)

  const int N = 64, S8 = 8;

  // ---- stage 0: edge pad ----
  pad_edge_k<<<64*52*132/THREADS, THREADS, 0, stream>>>(x, P);

  // ---- conv1: (64,1,52,132) -> (64,64,48,128) ----
  conv2d_k<1,64,52,132,48,128,5,0,8><<<dim3(64*48*128/THREADS, 64/8), THREADS, 0, stream>>>(P, c1w, T, N);
  bn2d_stats_partial<<<dim3(64, S8), THREADS, 0, stream>>>(T, PART, N, 64, 48*128, S8);
  bn2d_finalize<<<1, 64, 0, stream>>>(PART, g1, b1, SC, SH, 64, S8, 1.f/(N*48.f*128.f));
  bn_relu_pool_k<<<64*64*24*64/THREADS, THREADS, 0, stream>>>(T, U, SC, SH, N, 64, 48, 128);

  // ---- conv2: (64,64,24,64) -> (64,128,24,64) ----
  conv2d_k<64,128,24,64,24,64,5,2,8><<<dim3(64*24*64/THREADS, 128/8), THREADS, 0, stream>>>(U, c2w, T, N);
  bn2d_stats_partial<<<dim3(128, S8), THREADS, 0, stream>>>(T, PART, N, 128, 24*64, S8);
  bn2d_finalize<<<1, 128, 0, stream>>>(PART, g2, b2, SC, SH, 128, S8, 1.f/(N*24.f*64.f));
  bn_relu_pool_k<<<64*128*12*32/THREADS, THREADS, 0, stream>>>(T, U, SC, SH, N, 128, 24, 64);

  // ---- conv3: (64,128,12,32) -> (64,256,12,32) ----
  conv2d_k<128,256,12,32,12,32,3,1,8><<<dim3(64*12*32/THREADS, 256/8), THREADS, 0, stream>>>(U, c3w, T, N);
  bn2d_stats_partial<<<dim3(256, S8), THREADS, 0, stream>>>(T, PART, N, 256, 12*32, S8);
  bn2d_finalize<<<1, 256, 0, stream>>>(PART, g3, b3, SC, SH, 256, S8, 1.f/(N*12.f*32.f));
  bn_relu_inplace_k<<<64*256*12*32/THREADS, THREADS, 0, stream>>>(T, SC, SH, 64*256*12*32, 256, 12*32);

  // ---- conv4: (64,256,12,32) -> (64,512,12,32) ----
  conv2d_k<256,512,12,32,12,32,3,1,8><<<dim3(64*12*32/THREADS, 512/8), THREADS, 0, stream>>>(T, c4w, U, N);
  bn2d_stats_partial<<<dim3(512, S8), THREADS, 0, stream>>>(U, PART, N, 512, 12*32, S8);
  bn2d_finalize<<<2, 256, 0, stream>>>(PART, g4, b4, SC, SH, 512, S8, 1.f/(N*12.f*32.f));
  bn_relu_pool_k<<<64*512*6*16/THREADS, THREADS, 0, stream>>>(U, T, SC, SH, N, 512, 12, 32);

  // ---- conv5: (64,512,6,16) -> (64,512,6,16) ----
  conv2d_k<512,512,6,16,6,16,3,1,8><<<dim3(64*6*16/THREADS, 512/8), THREADS, 0, stream>>>(T, c5w, U, N);
  bn2d_stats_partial<<<dim3(512, S8), THREADS, 0, stream>>>(U, PART, N, 512, 6*16, S8);
  bn2d_finalize<<<2, 256, 0, stream>>>(PART, g5, b5, SC, SH, 512, S8, 1.f/(N*6.f*16.f));
  bn_relu_inplace_k<<<64*512*6*16/THREADS, THREADS, 0, stream>>>(U, SC, SH, 64*512*6*16, 512, 6*16);

  // ---- ROI SPP: feat (64,512,6,16) + roi (256,5) -> (256,3072) ----
  spp_k<<<dim3(2, 256), THREADS, 0, stream>>>(U, roi, S);

  // ---- FC1: (256,3072) @ (2048,3072)^T -> (256,2048), BN1d + ReLU ----
  gemm_bias_k<<<dim3(2048/64, 256/64), THREADS, 0, stream>>>(S, f1w, f1b, F1, 256, 2048, 3072, 3072, 3072);
  bn1d_stats_k<<<2048/256, 256, 0, stream>>>(F1, g6, b6, SC, SH, 256, 2048);
  bn1d_apply_relu_k<<<256*2048/THREADS, THREADS, 0, stream>>>(F1, SC, SH, 256*2048, 2048);

  // ---- concat + FC2: (256,7901) @ (2048,7901)^T -> (256,2048), BN1d + ReLU ----
  concat_k<<<256*7901/THREADS, THREADS, 0, stream>>>(F1, phoc, CC);
  gemm_bias_k<<<dim3(2048/64, 256/64), THREADS, 0, stream>>>(CC, f2w, f2b, out, 256, 2048, 7901, 7901, 7901);
  bn1d_stats_k<<<2048/256, 256, 0, stream>>>(out, g7, b7, SC, SH, 256, 2048);
  bn1d_apply_relu_k<<<256*2048/THREADS, THREADS, 0, stream>>>(out, SC, SH, 256*2048, 2048);
}

// Round 3
// 1553.911 us; speedup vs baseline: 5.0808x; 5.0808x over previous
//
#include <hip/hip_runtime.h>
#include <hip/hip_bf16.h>

// ============================================================================
// HWNet-SPP forward, MFMA bf16 implicit-GEMM with hi/lo split precision.
// Activations stored as bf16 (hi,lo) pairs -> effectively exact A operand.
// Conv weights split hi/lo too (3-pass GEMM); FC weights hi-only (2-pass).
// Conv/FC biases skipped (BN mean-subtraction cancels them exactly).
// ============================================================================

typedef __bf16 bf16;
using bf16x8 = __attribute__((ext_vector_type(8))) __bf16;
using f32x4  = __attribute__((ext_vector_type(4))) float;

__device__ __forceinline__ void split2(float v, bf16& h, bf16& l) {
  bf16 hb = (bf16)v;
  h = hb;
  l = (bf16)(v - (float)hb);
}

__device__ __forceinline__ void gld_lds16(const bf16* g, void* lds) {
  __builtin_amdgcn_global_load_lds(
      (const __attribute__((address_space(1))) unsigned int*)g,
      (__attribute__((address_space(3))) unsigned int*)lds, 16, 0, 0);
}

// ---------------- pad (edge mode, +2 each side of 48x128) ----------------
__global__ __launch_bounds__(256) void pad_edge_k(const float* __restrict__ x,
                                                  float* __restrict__ p) {
  int i = blockIdx.x * 256 + threadIdx.x;
  const int TOT = 64 * 52 * 132;
  if (i >= TOT) return;
  int w = i % 132; int t = i / 132; int h = t % 52; int n = t / 52;
  int sh = h - 2; sh = sh < 0 ? 0 : (sh > 47 ? 47 : sh);
  int sw = w - 2; sw = sw < 0 ? 0 : (sw > 127 ? 127 : sw);
  p[i] = x[(n * 48 + sh) * 128 + sw];
}

// ---------------- conv1 pass 1: BN stats only (fp32, recompute style) ------
// grid (96, 8): block covers 4096 pixels, channel group of 8.
__global__ __launch_bounds__(256) void conv1_stats_k(const float* __restrict__ P,
                                                     const float* __restrict__ wt,
                                                     float* __restrict__ part) {
  int co0 = blockIdx.y * 8;
  float sums[8] = {0.f}, sqs[8] = {0.f};
  for (int r = 0; r < 16; r++) {
    int pix = blockIdx.x * 4096 + r * 256 + threadIdx.x;  // 0..393215
    int w = pix & 127; int t = pix >> 7; int h = t % 48; int n = t / 48;
    const float* ip = P + ((size_t)n * 52 + h) * 132 + w;
    float win[25];
#pragma unroll
    for (int kh = 0; kh < 5; kh++)
#pragma unroll
      for (int kw = 0; kw < 5; kw++) win[kh * 5 + kw] = ip[kh * 132 + kw];
#pragma unroll
    for (int j = 0; j < 8; j++) {
      const float* wp = wt + (size_t)(co0 + j) * 25;
      float acc = 0.f;
#pragma unroll
      for (int k = 0; k < 25; k++) acc += win[k] * wp[k];
      sums[j] += acc; sqs[j] += acc * acc;
    }
  }
  __shared__ float ls[256], lq[256];
  for (int j = 0; j < 8; j++) {
    ls[threadIdx.x] = sums[j]; lq[threadIdx.x] = sqs[j];
    __syncthreads();
    for (int o = 128; o > 0; o >>= 1) {
      if (threadIdx.x < o) { ls[threadIdx.x] += ls[threadIdx.x + o]; lq[threadIdx.x] += lq[threadIdx.x + o]; }
      __syncthreads();
    }
    if (threadIdx.x == 0) {
      int c = co0 + j;
      part[((size_t)c * 96 + blockIdx.x) * 2 + 0] = ls[0];
      part[((size_t)c * 96 + blockIdx.x) * 2 + 1] = lq[0];
    }
    __syncthreads();
  }
}

// ---------------- conv1 pass 2: conv+BN+ReLU+pool+pad -> hi/lo -------------
// grid (384, 8): one thread per pooled pixel (64x24x64), 8 channels.
__global__ __launch_bounds__(256) void conv1_apply_k(const float* __restrict__ P,
                                                     const float* __restrict__ wt,
                                                     const float* __restrict__ scale,
                                                     const float* __restrict__ shift,
                                                     bf16* __restrict__ yh,
                                                     bf16* __restrict__ yl) {
  int pix = blockIdx.x * 256 + threadIdx.x;  // 0..98303
  int ow = pix & 63; int t = pix >> 6; int oh = t % 24; int n = t / 24;
  int co0 = blockIdx.y * 8;
  const float* ip = P + ((size_t)n * 52 + 2 * oh) * 132 + 2 * ow;
  float win[36];
#pragma unroll
  for (int r = 0; r < 6; r++)
#pragma unroll
    for (int c = 0; c < 6; c++) win[r * 6 + c] = ip[r * 132 + c];
  bf16x8 hv, lv;
#pragma unroll
  for (int j = 0; j < 8; j++) {
    const float* wp = wt + (size_t)(co0 + j) * 25;
    float sc = scale[co0 + j], sh = shift[co0 + j];
    float m = -1e30f;
#pragma unroll
    for (int dy = 0; dy < 2; dy++)
#pragma unroll
      for (int dx = 0; dx < 2; dx++) {
        float acc = 0.f;
#pragma unroll
        for (int kh = 0; kh < 5; kh++)
#pragma unroll
          for (int kw = 0; kw < 5; kw++)
            acc += win[(kh + dy) * 6 + kw + dx] * wp[kh * 5 + kw];
        m = fmaxf(m, acc * sc + sh);
      }
    float v = fmaxf(m, 0.f);
    bf16 h, l; split2(v, h, l);
    hv[j] = h; lv[j] = l;
  }
  size_t o = (((size_t)n * 28 + oh + 2) * 68 + ow + 2) * 64 + co0;
  *(bf16x8*)(yh + o) = hv;
  *(bf16x8*)(yl + o) = lv;
}

// ---------------- MFMA implicit-GEMM with hi/lo split ----------------------
// C[m,co] = (Ahi+Alo)[m,:] . (Bhi(+Blo))[co,:]
// A from padded NHWC bf16 [64][OH+KS-1][OW+KS-1][CI]; FC: KS=1,OH=OW=2.
// Tile 128x128, BK=64, 4 waves, st-swizzle via pre-swizzled source addrs.
template<int CI, int KS, int OH, int OW, int CO, bool BLO>
__global__ __launch_bounds__(256) void conv_gemm_k(const bf16* __restrict__ Ahi,
                                                   const bf16* __restrict__ Alo,
                                                   const bf16* __restrict__ Bhi,
                                                   const bf16* __restrict__ Blo,
                                                   float* __restrict__ Cout) {
  static_assert(CI % 64 == 0, "chunk must not straddle ci segments");
  constexpr int K = KS * KS * CI;
  constexpr int IWP = OW + KS - 1;
  constexpr int NCH = K / 64;
  __shared__ bf16 Ash[128 * 64];
  __shared__ bf16 Asl[128 * 64];
  __shared__ bf16 Bsh[128 * 64];
  __shared__ bf16 Bsl[BLO ? 128 * 64 : 64];
  const int t = threadIdx.x;
  const int lane = t & 63, w = t >> 6;
  const int m0 = blockIdx.x * 128, n0 = blockIdx.y * 128;

  // staging source precompute: issue i covers rows (i*4+w)*8 .. +8
  int apix[4]; size_t boff[4];
#pragma unroll
  for (int i = 0; i < 4; i++) {
    int f = (i * 4 + w) * 64 + lane;
    int row = f >> 3, slot = f & 7;
    int ss = slot ^ (row & 7);               // st-swizzle on source
    int m = m0 + row;
    int n = m / (OH * OW); int rem = m % (OH * OW);
    int oh = rem / OW, ow_ = rem % OW;
    apix[i] = ((n * (OH + KS - 1) + oh) * IWP + ow_) * CI + ss * 8;
    boff[i] = (size_t)(n0 + row) * K + ss * 8;
  }

  // ds_read fragment addresses
  const int wrow = w >> 1, wcol = w & 1;
  const int kg = lane >> 4;
  int arb[4], amk[4], brb[4], bmk[4];
#pragma unroll
  for (int q = 0; q < 4; q++) {
    int ra = wrow * 64 + q * 16 + (lane & 15);
    arb[q] = ra * 128; amk[q] = ra & 7;
    int rb = wcol * 64 + q * 16 + (lane & 15);
    brb[q] = rb * 128; bmk[q] = rb & 7;
  }
  const char* Ashb = (const char*)Ash;
  const char* Aslb = (const char*)Asl;
  const char* Bshb = (const char*)Bsh;
  const char* Bslb = (const char*)Bsl;

  f32x4 acc[4][4] = {};
  for (int kc = 0; kc < NCH; ++kc) {
    const int k0 = kc * 64;
    const int seg = k0 / CI;
    const int ci0 = k0 % CI;
    const int kh = seg / KS, kw = seg % KS;
    const int aoff = (kh * IWP + kw) * CI + ci0;   // wave-uniform
#pragma unroll
    for (int i = 0; i < 4; i++) {
      gld_lds16(Ahi + (size_t)apix[i] + aoff, (char*)Ash + (i * 4 + w) * 1024);
      gld_lds16(Alo + (size_t)apix[i] + aoff, (char*)Asl + (i * 4 + w) * 1024);
      gld_lds16(Bhi + boff[i] + k0,           (char*)Bsh + (i * 4 + w) * 1024);
      if (BLO)
        gld_lds16(Blo + boff[i] + k0,         (char*)Bsl + (i * 4 + w) * 1024);
    }
    __syncthreads();
#pragma unroll
    for (int ks = 0; ks < 2; ks++) {
      const int slot = ks * 4 + kg;
      bf16x8 ah[4], al[4], bh[4];
#pragma unroll
      for (int q = 0; q < 4; q++) {
        ah[q] = *(const bf16x8*)(Ashb + arb[q] + ((slot ^ amk[q]) << 4));
        al[q] = *(const bf16x8*)(Aslb + arb[q] + ((slot ^ amk[q]) << 4));
        bh[q] = *(const bf16x8*)(Bshb + brb[q] + ((slot ^ bmk[q]) << 4));
      }
#pragma unroll
      for (int mi = 0; mi < 4; mi++)
#pragma unroll
        for (int ni = 0; ni < 4; ni++)
          acc[mi][ni] = __builtin_amdgcn_mfma_f32_16x16x32_bf16(ah[mi], bh[ni], acc[mi][ni], 0, 0, 0);
#pragma unroll
      for (int mi = 0; mi < 4; mi++)
#pragma unroll
        for (int ni = 0; ni < 4; ni++)
          acc[mi][ni] = __builtin_amdgcn_mfma_f32_16x16x32_bf16(al[mi], bh[ni], acc[mi][ni], 0, 0, 0);
      if (BLO) {
        bf16x8 bl[4];
#pragma unroll
        for (int q = 0; q < 4; q++)
          bl[q] = *(const bf16x8*)(Bslb + brb[q] + ((slot ^ bmk[q]) << 4));
#pragma unroll
        for (int mi = 0; mi < 4; mi++)
#pragma unroll
          for (int ni = 0; ni < 4; ni++)
            acc[mi][ni] = __builtin_amdgcn_mfma_f32_16x16x32_bf16(ah[mi], bl[ni], acc[mi][ni], 0, 0, 0);
      }
    }
    __syncthreads();
  }

  // epilogue: D row = (lane>>4)*4 + jj, col = lane&15
  const int crow0 = (lane >> 4) * 4, ccol = lane & 15;
#pragma unroll
  for (int mi = 0; mi < 4; mi++) {
    int m = m0 + wrow * 64 + mi * 16 + crow0;
#pragma unroll
    for (int ni = 0; ni < 4; ni++) {
      int nn = n0 + wcol * 64 + ni * 16 + ccol;
      float* cp = Cout + (size_t)m * CO + nn;
#pragma unroll
      for (int jj = 0; jj < 4; jj++) cp[(size_t)jj * CO] = acc[mi][ni][jj];
    }
  }
}

// ---------------- BN stats over NHWC [M][CO] fp32 (deterministic) ----------
__global__ __launch_bounds__(256) void bn_stats_nhwc(const float* __restrict__ x,
                                                     float* __restrict__ part,
                                                     int M, int CO, int NS) {
  int c = blockIdx.x * 64 + (threadIdx.x & 63);
  int s = blockIdx.y;
  int rl = threadIdx.x >> 6;
  int rows = M / NS, r0 = s * rows;
  float sum = 0.f, sq = 0.f;
  for (int r = r0 + rl; r < r0 + rows; r += 4) {
    float v = x[(size_t)r * CO + c];
    sum += v; sq += v * v;
  }
  __shared__ float ls[256], lq[256];
  ls[threadIdx.x] = sum; lq[threadIdx.x] = sq;
  __syncthreads();
  if (threadIdx.x < 64) {
    sum = ls[threadIdx.x] + ls[threadIdx.x + 64] + ls[threadIdx.x + 128] + ls[threadIdx.x + 192];
    sq  = lq[threadIdx.x] + lq[threadIdx.x + 64] + lq[threadIdx.x + 128] + lq[threadIdx.x + 192];
    part[((size_t)c * NS + s) * 2 + 0] = sum;
    part[((size_t)c * NS + s) * 2 + 1] = sq;
  }
}

__global__ void bn_finalize(const float* __restrict__ part,
                            const float* __restrict__ g, const float* __restrict__ b,
                            float* __restrict__ scale, float* __restrict__ shift,
                            int C, int S, float invCount) {
  int c = blockIdx.x * blockDim.x + threadIdx.x;
  if (c >= C) return;
  float sum = 0.f, sq = 0.f;
  for (int s = 0; s < S; s++) { sum += part[((size_t)c * S + s) * 2]; sq += part[((size_t)c * S + s) * 2 + 1]; }
  float m = sum * invCount;
  float var = sq * invCount - m * m;
  float sc = g[c] * rsqrtf(var + 1e-5f);
  scale[c] = sc;
  shift[c] = b[c] - m * sc;
}

// ---------------- fused BN + ReLU (+2x2 pool) + pad, fp32 -> hi/lo ---------
template<int CO, int IH, int IW, bool POOL, int PADO>
__global__ __launch_bounds__(256) void bn_act_pad_k(const float* __restrict__ x,
                                                    const float* __restrict__ scale,
                                                    const float* __restrict__ shift,
                                                    bf16* __restrict__ yh,
                                                    bf16* __restrict__ yl) {
  constexpr int OH2 = POOL ? IH / 2 : IH, OW2 = POOL ? IW / 2 : IW;
  constexpr int OHP = OH2 + 2 * PADO, OWP = OW2 + 2 * PADO;
  int i = blockIdx.x * 256 + threadIdx.x;
  if (i >= 64 * OH2 * OW2 * CO) return;
  int c = i % CO; int t = i / CO; int ow = t % OW2; t /= OW2; int oh = t % OH2; int n = t / OH2;
  float sc = scale[c], sh = shift[c];
  float v;
  if (POOL) {
    const float* p = x + (((size_t)(n * IH) + oh * 2) * IW + ow * 2) * CO + c;
    float a = p[0] * sc + sh;
    float b2 = p[CO] * sc + sh;
    float d = p[(size_t)IW * CO] * sc + sh;
    float e = p[(size_t)(IW + 1) * CO] * sc + sh;
    v = fmaxf(fmaxf(a, b2), fmaxf(d, e));
  } else {
    v = x[(size_t)i] * sc + sh;
  }
  v = fmaxf(v, 0.f);
  bf16 h, l; split2(v, h, l);
  size_t o = (((size_t)(n * OHP) + oh + PADO) * OWP + ow + PADO) * CO + c;
  yh[o] = h; yl[o] = l;
}

// ---------------- ROI SPP: feat hi/lo [64][6][16][512] -> S hi/lo ----------
__global__ __launch_bounds__(256) void spp_k(const bf16* __restrict__ fh,
                                             const bf16* __restrict__ fl,
                                             const int* __restrict__ roi,
                                             bf16* __restrict__ oh_,
                                             bf16* __restrict__ ol_) {
  int c = blockIdx.x * 256 + threadIdx.x;  // 0..511
  int r = blockIdx.y;                      // 0..255
  const int* rp = roi + r * 5;
  int im = rp[0];
  int c1 = rp[1] >> 3, r1 = rp[2] >> 3, c2 = rp[3] >> 3, r2 = rp[4] >> 3;
  int w = c2 - c1 + 1;
  int lo[6], hi[6];
  int bi = 0;
#pragma unroll
  for (int l = 1; l <= 3; l++)
    for (int k = 0; k < l; k++) {
      lo[bi] = c1 + (k * w) / l;
      hi[bi] = c1 + ((k + 1) * w + l - 1) / l - 1;
      bi++;
    }
  float mx[6];
#pragma unroll
  for (int b = 0; b < 6; b++) mx[b] = -1e30f;
  const bf16* ph = fh + (size_t)im * 96 * 512 + c;
  const bf16* pl = fl + (size_t)im * 96 * 512 + c;
  for (int row = r1; row <= r2; row++)
    for (int col = c1; col <= c2; col++) {
      size_t off = (size_t)(row * 16 + col) * 512;
      float v = (float)ph[off] + (float)pl[off];
#pragma unroll
      for (int b = 0; b < 6; b++)
        if (col >= lo[b] && col <= hi[b]) mx[b] = fmaxf(mx[b], v);
    }
  int idx[6] = {c, 512 + c * 2, 512 + c * 2 + 1, 1536 + c * 3, 1536 + c * 3 + 1, 1536 + c * 3 + 2};
#pragma unroll
  for (int b = 0; b < 6; b++) {
    bf16 h, l; split2(mx[b], h, l);
    oh_[(size_t)r * 3072 + idx[b]] = h;
    ol_[(size_t)r * 3072 + idx[b]] = l;
  }
}

// ---------------- BN1d ----------------
__global__ void bn1d_stats_k(const float* __restrict__ x,
                             const float* __restrict__ g, const float* __restrict__ b,
                             float* __restrict__ scale, float* __restrict__ shift,
                             int R, int F) {
  int f = blockIdx.x * blockDim.x + threadIdx.x;
  if (f >= F) return;
  float sum = 0.f, sq = 0.f;
  for (int r = 0; r < R; r++) {
    float v = x[(size_t)r * F + f];
    sum += v; sq += v * v;
  }
  float invR = 1.f / (float)R;
  float m = sum * invR;
  float var = sq * invR - m * m;
  float sc = g[f] * rsqrtf(var + 1e-5f);
  scale[f] = sc;
  shift[f] = b[f] - m * sc;
}

// FC1: BN+ReLU, write hi/lo into CC[:, 0:2048] (ld 7936)
__global__ __launch_bounds__(256) void bn1d_apply_cc_k(const float* __restrict__ x,
                                                       const float* __restrict__ scale,
                                                       const float* __restrict__ shift,
                                                       bf16* __restrict__ ch,
                                                       bf16* __restrict__ cl) {
  int i = blockIdx.x * 256 + threadIdx.x;
  if (i >= 256 * 2048) return;
  int f = i & 2047, r = i >> 11;
  float v = fmaxf(x[i] * scale[f] + shift[f], 0.f);
  bf16 h, l; split2(v, h, l);
  ch[(size_t)r * 7936 + f] = h;
  cl[(size_t)r * 7936 + f] = l;
}

// FC2: BN+ReLU, fp32 out
__global__ __launch_bounds__(256) void bn1d_apply_f32_k(const float* __restrict__ x,
                                                        const float* __restrict__ scale,
                                                        const float* __restrict__ shift,
                                                        float* __restrict__ y) {
  int i = blockIdx.x * 256 + threadIdx.x;
  if (i >= 256 * 2048) return;
  int f = i & 2047;
  y[i] = fmaxf(x[i] * scale[f] + shift[f], 0.f);
}

// ---------------- weight transforms ----------------
// OIHW fp32 -> [CO][KH][KW][CI] bf16 hi + lo
template<int CI, int CO, int KS>
__global__ __launch_bounds__(256) void wconv_k(const float* __restrict__ w,
                                               bf16* __restrict__ oh_,
                                               bf16* __restrict__ ol_) {
  int i = blockIdx.x * 256 + threadIdx.x;
  if (i >= CO * KS * KS * CI) return;
  int ci = i % CI; int t = i / CI; int kw = t % KS; t /= KS; int kh = t % KS; int co = t / KS;
  float v = w[(((size_t)co * CI + ci) * KS + kh) * KS + kw];
  bf16 h, l; split2(v, h, l);
  oh_[i] = h; ol_[i] = l;
}

__global__ __launch_bounds__(256) void cast_k(const float* __restrict__ x,
                                              bf16* __restrict__ y, int n) {
  int i = blockIdx.x * 256 + threadIdx.x;
  if (i < n) y[i] = (bf16)x[i];
}

// f2w [2048][7901] fp32 -> [2048][7936] bf16 hi (zero tail)
__global__ __launch_bounds__(256) void wfc2_k(const float* __restrict__ x,
                                              bf16* __restrict__ y) {
  int i = blockIdx.x * 256 + threadIdx.x;
  if (i >= 2048 * 7936) return;
  int k = i % 7936, n = i / 7936;
  y[i] = (bf16)(k < 7901 ? x[(size_t)n * 7901 + k] : 0.f);
}

// phoc [256][5853] fp32 -> CC[:, 2048:7936] hi/lo (zero tail cols)
__global__ __launch_bounds__(256) void phoc_cc_k(const float* __restrict__ phoc,
                                                 bf16* __restrict__ ch,
                                                 bf16* __restrict__ cl) {
  int i = blockIdx.x * 256 + threadIdx.x;
  if (i >= 256 * 5888) return;
  int k = i % 5888, r = i / 5888;
  int col = 2048 + k;
  float v = (col < 7901) ? phoc[(size_t)r * 5853 + (col - 2048)] : 0.f;
  bf16 h, l; split2(v, h, l);
  ch[(size_t)r * 7936 + col] = h;
  cl[(size_t)r * 7936 + col] = l;
}

// ============================================================================
extern "C" void kernel_launch(void* const* d_in, const int* in_sizes, int n_in,
                              void* d_out, int out_size, void* d_ws, size_t ws_size,
                              hipStream_t stream) {
  (void)in_sizes; (void)n_in; (void)out_size; (void)ws_size;

  const float* x    = (const float*)d_in[0];
  const int*   roi  = (const int*)  d_in[1];
  const float* phoc = (const float*)d_in[2];
  const float* c1w  = (const float*)d_in[3];
  const float* g1   = (const float*)d_in[5];
  const float* b1   = (const float*)d_in[6];
  const float* c2w  = (const float*)d_in[7];
  const float* g2   = (const float*)d_in[9];
  const float* b2   = (const float*)d_in[10];
  const float* c3w  = (const float*)d_in[11];
  const float* g3   = (const float*)d_in[13];
  const float* b3   = (const float*)d_in[14];
  const float* c4w  = (const float*)d_in[15];
  const float* g4   = (const float*)d_in[17];
  const float* b4   = (const float*)d_in[18];
  const float* c5w  = (const float*)d_in[19];
  const float* g5   = (const float*)d_in[21];
  const float* b5   = (const float*)d_in[22];
  const float* f1w  = (const float*)d_in[23];
  const float* g6   = (const float*)d_in[25];
  const float* b6   = (const float*)d_in[26];
  const float* f2w  = (const float*)d_in[27];
  const float* g7   = (const float*)d_in[29];
  const float* b7   = (const float*)d_in[30];
  float* out = (float*)d_out;

  // ---- workspace layout (total ~166.3 MB) ----
  char* ws = (char*)d_ws;
  float* P    = (float*)(ws + 0x0000000);   // 1.76 MB
  bf16*  Ahi  = (bf16*) (ws + 0x0200000);   // 16 MB
  bf16*  Alo  = (bf16*) (ws + 0x1200000);   // 16 MB
  float* C    = (float*)(ws + 0x2200000);   // 51 MB
  bf16*  Wc2h = (bf16*) (ws + 0x5500000);
  bf16*  Wc3h = (bf16*) (ws + 0x5570000);
  bf16*  Wc4h = (bf16*) (ws + 0x5600000);
  bf16*  Wc5h = (bf16*) (ws + 0x5840000);
  bf16*  Wf1  = (bf16*) (ws + 0x5CC0000);
  bf16*  Wf2  = (bf16*) (ws + 0x68C0000);
  bf16*  Wc2l = (bf16*) (ws + 0x87C0000);
  bf16*  Wc3l = (bf16*) (ws + 0x8830000);
  bf16*  Wc4l = (bf16*) (ws + 0x88C0000);
  bf16*  Wc5l = (bf16*) (ws + 0x8B00000);
  bf16*  Shi  = (bf16*) (ws + 0x8F80000);   // spp out hi [256][3072]
  bf16*  Slo  = (bf16*) (ws + 0x9100000);
  float* G6   = (float*)(ws + 0x9280000);   // fc1 out fp32 [256][2048]
  bf16*  CChi = (bf16*) (ws + 0x9480000);   // concat hi [256][7936]
  bf16*  CClo = (bf16*) (ws + 0x9860000);
  float* G7   = (float*)(ws + 0x9C40000);   // fc2 out fp32 [256][2048]
  float* PART = (float*)(ws + 0x9E40000);
  float* SC   = (float*)(ws + 0x9E80000);
  float* SH   = (float*)(ws + 0x9E90000);

  // ---- weight transforms ----
  wconv_k<64, 128, 5><<<800, 256, 0, stream>>>(c2w, Wc2h, Wc2l);
  wconv_k<128, 256, 3><<<1152, 256, 0, stream>>>(c3w, Wc3h, Wc3l);
  wconv_k<256, 512, 3><<<4608, 256, 0, stream>>>(c4w, Wc4h, Wc4l);
  wconv_k<512, 512, 3><<<9216, 256, 0, stream>>>(c5w, Wc5h, Wc5l);
  cast_k<<<24576, 256, 0, stream>>>(f1w, Wf1, 2048 * 3072);
  wfc2_k<<<63488, 256, 0, stream>>>(f2w, Wf2);
  phoc_cc_k<<<5888, 256, 0, stream>>>(phoc, CChi, CClo);

  // ---- conv1 (two-pass, no big fp32 buffer) ----
  pad_edge_k<<<1716, 256, 0, stream>>>(x, P);
  conv1_stats_k<<<dim3(96, 8), 256, 0, stream>>>(P, c1w, PART);
  bn_finalize<<<1, 64, 0, stream>>>(PART, g1, b1, SC, SH, 64, 96, 1.f / 393216.f);
  hipMemsetAsync(Ahi, 0, (size_t)64 * 28 * 68 * 64 * 2, stream);
  hipMemsetAsync(Alo, 0, (size_t)64 * 28 * 68 * 64 * 2, stream);
  conv1_apply_k<<<dim3(384, 8), 256, 0, stream>>>(P, c1w, SC, SH, Ahi, Alo);

  // ---- conv2: A[98304][1600] -> C[98304][128] ----
  conv_gemm_k<64, 5, 24, 64, 128, true><<<dim3(768, 1), 256, 0, stream>>>(Ahi, Alo, Wc2h, Wc2l, C);
  bn_stats_nhwc<<<dim3(2, 32), 256, 0, stream>>>(C, PART, 98304, 128, 32);
  bn_finalize<<<1, 128, 0, stream>>>(PART, g2, b2, SC, SH, 128, 32, 1.f / 98304.f);
  hipMemsetAsync(Ahi, 0, (size_t)64 * 14 * 34 * 128 * 2, stream);
  hipMemsetAsync(Alo, 0, (size_t)64 * 14 * 34 * 128 * 2, stream);
  bn_act_pad_k<128, 24, 64, true, 1><<<12288, 256, 0, stream>>>(C, SC, SH, Ahi, Alo);

  // ---- conv3 ----
  conv_gemm_k<128, 3, 12, 32, 256, true><<<dim3(192, 2), 256, 0, stream>>>(Ahi, Alo, Wc3h, Wc3l, C);
  bn_stats_nhwc<<<dim3(4, 16), 256, 0, stream>>>(C, PART, 24576, 256, 16);
  bn_finalize<<<1, 256, 0, stream>>>(PART, g3, b3, SC, SH, 256, 16, 1.f / 24576.f);
  hipMemsetAsync(Ahi, 0, (size_t)64 * 14 * 34 * 256 * 2, stream);
  hipMemsetAsync(Alo, 0, (size_t)64 * 14 * 34 * 256 * 2, stream);
  bn_act_pad_k<256, 12, 32, false, 1><<<24576, 256, 0, stream>>>(C, SC, SH, Ahi, Alo);

  // ---- conv4 ----
  conv_gemm_k<256, 3, 12, 32, 512, true><<<dim3(192, 4), 256, 0, stream>>>(Ahi, Alo, Wc4h, Wc4l, C);
  bn_stats_nhwc<<<dim3(8, 16), 256, 0, stream>>>(C, PART, 24576, 512, 16);
  bn_finalize<<<2, 256, 0, stream>>>(PART, g4, b4, SC, SH, 512, 16, 1.f / 24576.f);
  hipMemsetAsync(Ahi, 0, (size_t)64 * 8 * 18 * 512 * 2, stream);
  hipMemsetAsync(Alo, 0, (size_t)64 * 8 * 18 * 512 * 2, stream);
  bn_act_pad_k<512, 12, 32, true, 1><<<12288, 256, 0, stream>>>(C, SC, SH, Ahi, Alo);

  // ---- conv5 ----
  conv_gemm_k<512, 3, 6, 16, 512, true><<<dim3(48, 4), 256, 0, stream>>>(Ahi, Alo, Wc5h, Wc5l, C);
  bn_stats_nhwc<<<dim3(8, 8), 256, 0, stream>>>(C, PART, 6144, 512, 8);
  bn_finalize<<<2, 256, 0, stream>>>(PART, g5, b5, SC, SH, 512, 8, 1.f / 6144.f);
  bn_act_pad_k<512, 6, 16, false, 0><<<12288, 256, 0, stream>>>(C, SC, SH, Ahi, Alo);  // feat

  // ---- SPP ----
  spp_k<<<dim3(2, 256), 256, 0, stream>>>(Ahi, Alo, roi, Shi, Slo);

  // ---- FC1: [256][3072] x [2048][3072] ----
  conv_gemm_k<3072, 1, 2, 2, 2048, false><<<dim3(2, 16), 256, 0, stream>>>(Shi, Slo, Wf1, nullptr, G6);
  bn1d_stats_k<<<8, 256, 0, stream>>>(G6, g6, b6, SC, SH, 256, 2048);
  bn1d_apply_cc_k<<<2048, 256, 0, stream>>>(G6, SC, SH, CChi, CClo);

  // ---- FC2: [256][7936] x [2048][7936] ----
  conv_gemm_k<7936, 1, 2, 2, 2048, false><<<dim3(2, 16), 256, 0, stream>>>(CChi, CClo, Wf2, nullptr, G7);
  bn1d_stats_k<<<8, 256, 0, stream>>>(G7, g7, b7, SC, SH, 256, 2048);
  bn1d_apply_f32_k<<<2048, 256, 0, stream>>>(G7, SC, SH, out);
}

// Round 4
// 1138.699 us; speedup vs baseline: 6.9334x; 1.3646x over previous
//
#include <hip/hip_runtime.h>
#include <hip/hip_bf16.h>

// ============================================================================
// HWNet-SPP forward, MFMA bf16 implicit-GEMM with hi/lo split precision.
// Activations stored as bf16 (hi,lo) pairs -> effectively exact A operand.
// Conv weights split hi/lo too (3-pass GEMM); FC weights hi-only (2-pass).
// BN column stats are fused into the GEMM epilogue (per-block partials).
// Conv/FC biases skipped (BN mean-subtraction cancels them exactly).
// ============================================================================

typedef __bf16 bf16;
using bf16x8 = __attribute__((ext_vector_type(8))) __bf16;
using f32x4  = __attribute__((ext_vector_type(4))) float;

__device__ __forceinline__ void split2(float v, bf16& h, bf16& l) {
  bf16 hb = (bf16)v;
  h = hb;
  l = (bf16)(v - (float)hb);
}

__device__ __forceinline__ void gld_lds16(const bf16* g, void* lds) {
  __builtin_amdgcn_global_load_lds(
      (const __attribute__((address_space(1))) unsigned int*)g,
      (__attribute__((address_space(3))) unsigned int*)lds, 16, 0, 0);
}

// ---------------- pad (edge mode, +2 each side of 48x128) ----------------
__global__ __launch_bounds__(256) void pad_edge_k(const float* __restrict__ x,
                                                  float* __restrict__ p) {
  int i = blockIdx.x * 256 + threadIdx.x;
  const int TOT = 64 * 52 * 132;
  if (i >= TOT) return;
  int w = i % 132; int t = i / 132; int h = t % 52; int n = t / 52;
  int sh = h - 2; sh = sh < 0 ? 0 : (sh > 47 ? 47 : sh);
  int sw = w - 2; sw = sw < 0 ? 0 : (sw > 127 ? 127 : sw);
  p[i] = x[(n * 48 + sh) * 128 + sw];
}

// ---------------- conv1 pass 1: BN stats only (fp32, recompute style) ------
__global__ __launch_bounds__(256) void conv1_stats_k(const float* __restrict__ P,
                                                     const float* __restrict__ wt,
                                                     float* __restrict__ part) {
  int co0 = blockIdx.y * 8;
  float sums[8] = {0.f}, sqs[8] = {0.f};
  for (int r = 0; r < 16; r++) {
    int pix = blockIdx.x * 4096 + r * 256 + threadIdx.x;  // 0..393215
    int w = pix & 127; int t = pix >> 7; int h = t % 48; int n = t / 48;
    const float* ip = P + ((size_t)n * 52 + h) * 132 + w;
    float win[25];
#pragma unroll
    for (int kh = 0; kh < 5; kh++)
#pragma unroll
      for (int kw = 0; kw < 5; kw++) win[kh * 5 + kw] = ip[kh * 132 + kw];
#pragma unroll
    for (int j = 0; j < 8; j++) {
      const float* wp = wt + (size_t)(co0 + j) * 25;
      float acc = 0.f;
#pragma unroll
      for (int k = 0; k < 25; k++) acc += win[k] * wp[k];
      sums[j] += acc; sqs[j] += acc * acc;
    }
  }
  __shared__ float ls[256], lq[256];
  for (int j = 0; j < 8; j++) {
    ls[threadIdx.x] = sums[j]; lq[threadIdx.x] = sqs[j];
    __syncthreads();
    for (int o = 128; o > 0; o >>= 1) {
      if (threadIdx.x < o) { ls[threadIdx.x] += ls[threadIdx.x + o]; lq[threadIdx.x] += lq[threadIdx.x + o]; }
      __syncthreads();
    }
    if (threadIdx.x == 0) {
      int c = co0 + j;
      part[((size_t)c * 96 + blockIdx.x) * 2 + 0] = ls[0];
      part[((size_t)c * 96 + blockIdx.x) * 2 + 1] = lq[0];
    }
    __syncthreads();
  }
}

// ---------------- conv1 pass 2: conv+BN+ReLU+pool+pad -> hi/lo -------------
__global__ __launch_bounds__(256) void conv1_apply_k(const float* __restrict__ P,
                                                     const float* __restrict__ wt,
                                                     const float* __restrict__ scale,
                                                     const float* __restrict__ shift,
                                                     bf16* __restrict__ yh,
                                                     bf16* __restrict__ yl) {
  int pix = blockIdx.x * 256 + threadIdx.x;  // 0..98303
  int ow = pix & 63; int t = pix >> 6; int oh = t % 24; int n = t / 24;
  int co0 = blockIdx.y * 8;
  const float* ip = P + ((size_t)n * 52 + 2 * oh) * 132 + 2 * ow;
  float win[36];
#pragma unroll
  for (int r = 0; r < 6; r++)
#pragma unroll
    for (int c = 0; c < 6; c++) win[r * 6 + c] = ip[r * 132 + c];
  bf16x8 hv, lv;
#pragma unroll
  for (int j = 0; j < 8; j++) {
    const float* wp = wt + (size_t)(co0 + j) * 25;
    float sc = scale[co0 + j], sh = shift[co0 + j];
    float m = -1e30f;
#pragma unroll
    for (int dy = 0; dy < 2; dy++)
#pragma unroll
      for (int dx = 0; dx < 2; dx++) {
        float acc = 0.f;
#pragma unroll
        for (int kh = 0; kh < 5; kh++)
#pragma unroll
          for (int kw = 0; kw < 5; kw++)
            acc += win[(kh + dy) * 6 + kw + dx] * wp[kh * 5 + kw];
        m = fmaxf(m, acc * sc + sh);
      }
    float v = fmaxf(m, 0.f);
    bf16 h, l; split2(v, h, l);
    hv[j] = h; lv[j] = l;
  }
  size_t o = (((size_t)n * 28 + oh + 2) * 68 + ow + 2) * 64 + co0;
  *(bf16x8*)(yh + o) = hv;
  *(bf16x8*)(yl + o) = lv;
}

// ---------------- MFMA implicit-GEMM with hi/lo split + fused BN partials --
// C[m,co] = (Ahi+Alo)[m,:] . (Bhi(+Blo))[co,:]
// A from padded NHWC bf16 [64][OH+KS-1][OW+KS-1][CI]; FC: KS=1,OH=OW=2.
// Tile 128x128, BK=64, 4 waves, st-swizzle via pre-swizzled source addrs.
// Epilogue also emits per-block per-column (sum, sumsq) partials:
//   part[(col)*gridDim.x + blockIdx.x] = {sum, sumsq} over this block's rows.
template<int CI, int KS, int OH, int OW, int CO, bool BLO>
__global__ __launch_bounds__(256) void conv_gemm_k(const bf16* __restrict__ Ahi,
                                                   const bf16* __restrict__ Alo,
                                                   const bf16* __restrict__ Bhi,
                                                   const bf16* __restrict__ Blo,
                                                   float* __restrict__ Cout,
                                                   float* __restrict__ part) {
  static_assert(CI % 64 == 0, "chunk must not straddle ci segments");
  constexpr int K = KS * KS * CI;
  constexpr int IWP = OW + KS - 1;
  constexpr int NCH = K / 64;
  __shared__ bf16 Ash[128 * 64];
  __shared__ bf16 Asl[128 * 64];
  __shared__ bf16 Bsh[128 * 64];
  __shared__ bf16 Bsl[BLO ? 128 * 64 : 64];
  __shared__ float red[2][128][8];
  const int t = threadIdx.x;
  const int lane = t & 63, w = t >> 6;
  const int m0 = blockIdx.x * 128, n0 = blockIdx.y * 128;

  // staging source precompute: issue i covers rows (i*4+w)*8 .. +8
  int apix[4]; size_t boff[4];
#pragma unroll
  for (int i = 0; i < 4; i++) {
    int f = (i * 4 + w) * 64 + lane;
    int row = f >> 3, slot = f & 7;
    int ss = slot ^ (row & 7);               // st-swizzle on source
    int m = m0 + row;
    int n = m / (OH * OW); int rem = m % (OH * OW);
    int oh = rem / OW, ow_ = rem % OW;
    apix[i] = ((n * (OH + KS - 1) + oh) * IWP + ow_) * CI + ss * 8;
    boff[i] = (size_t)(n0 + row) * K + ss * 8;
  }

  // ds_read fragment addresses
  const int wrow = w >> 1, wcol = w & 1;
  const int kg = lane >> 4;
  int arb[4], amk[4], brb[4], bmk[4];
#pragma unroll
  for (int q = 0; q < 4; q++) {
    int ra = wrow * 64 + q * 16 + (lane & 15);
    arb[q] = ra * 128; amk[q] = ra & 7;
    int rb = wcol * 64 + q * 16 + (lane & 15);
    brb[q] = rb * 128; bmk[q] = rb & 7;
  }
  const char* Ashb = (const char*)Ash;
  const char* Aslb = (const char*)Asl;
  const char* Bshb = (const char*)Bsh;
  const char* Bslb = (const char*)Bsl;

  f32x4 acc[4][4] = {};
  for (int kc = 0; kc < NCH; ++kc) {
    const int k0 = kc * 64;
    const int seg = k0 / CI;
    const int ci0 = k0 % CI;
    const int kh = seg / KS, kw = seg % KS;
    const int aoff = (kh * IWP + kw) * CI + ci0;   // wave-uniform
#pragma unroll
    for (int i = 0; i < 4; i++) {
      gld_lds16(Ahi + (size_t)apix[i] + aoff, (char*)Ash + (i * 4 + w) * 1024);
      gld_lds16(Alo + (size_t)apix[i] + aoff, (char*)Asl + (i * 4 + w) * 1024);
      gld_lds16(Bhi + boff[i] + k0,           (char*)Bsh + (i * 4 + w) * 1024);
      if (BLO)
        gld_lds16(Blo + boff[i] + k0,         (char*)Bsl + (i * 4 + w) * 1024);
    }
    __syncthreads();
#pragma unroll
    for (int ks = 0; ks < 2; ks++) {
      const int slot = ks * 4 + kg;
      bf16x8 ah[4], al[4], bh[4];
#pragma unroll
      for (int q = 0; q < 4; q++) {
        ah[q] = *(const bf16x8*)(Ashb + arb[q] + ((slot ^ amk[q]) << 4));
        al[q] = *(const bf16x8*)(Aslb + arb[q] + ((slot ^ amk[q]) << 4));
        bh[q] = *(const bf16x8*)(Bshb + brb[q] + ((slot ^ bmk[q]) << 4));
      }
#pragma unroll
      for (int mi = 0; mi < 4; mi++)
#pragma unroll
        for (int ni = 0; ni < 4; ni++)
          acc[mi][ni] = __builtin_amdgcn_mfma_f32_16x16x32_bf16(ah[mi], bh[ni], acc[mi][ni], 0, 0, 0);
#pragma unroll
      for (int mi = 0; mi < 4; mi++)
#pragma unroll
        for (int ni = 0; ni < 4; ni++)
          acc[mi][ni] = __builtin_amdgcn_mfma_f32_16x16x32_bf16(al[mi], bh[ni], acc[mi][ni], 0, 0, 0);
      if (BLO) {
        bf16x8 bl[4];
#pragma unroll
        for (int q = 0; q < 4; q++)
          bl[q] = *(const bf16x8*)(Bslb + brb[q] + ((slot ^ bmk[q]) << 4));
#pragma unroll
        for (int mi = 0; mi < 4; mi++)
#pragma unroll
          for (int ni = 0; ni < 4; ni++)
            acc[mi][ni] = __builtin_amdgcn_mfma_f32_16x16x32_bf16(ah[mi], bl[ni], acc[mi][ni], 0, 0, 0);
      }
    }
    __syncthreads();
  }

  // epilogue: D row = (lane>>4)*4 + jj, col = lane&15
  const int crow0 = (lane >> 4) * 4, ccol = lane & 15;
  const int contrib = kg * 2 + wrow;  // 8 contributors per column
#pragma unroll
  for (int mi = 0; mi < 4; mi++) {
    int m = m0 + wrow * 64 + mi * 16 + crow0;
#pragma unroll
    for (int ni = 0; ni < 4; ni++) {
      int nn = n0 + wcol * 64 + ni * 16 + ccol;
      float* cp = Cout + (size_t)m * CO + nn;
#pragma unroll
      for (int jj = 0; jj < 4; jj++) cp[(size_t)jj * CO] = acc[mi][ni][jj];
    }
  }
  // fused BN partials: per-thread 16-row sums per owned column
#pragma unroll
  for (int ni = 0; ni < 4; ni++) {
    float s = 0.f, q = 0.f;
#pragma unroll
    for (int mi = 0; mi < 4; mi++)
#pragma unroll
      for (int jj = 0; jj < 4; jj++) {
        float v = acc[mi][ni][jj];
        s += v; q += v * v;
      }
    int coll = wcol * 64 + ni * 16 + ccol;
    red[0][coll][contrib] = s;
    red[1][coll][contrib] = q;
  }
  __syncthreads();
  if (t < 128) {
    float s = 0.f, q = 0.f;
#pragma unroll
    for (int j = 0; j < 8; j++) { s += red[0][t][j]; q += red[1][t][j]; }
    size_t c = n0 + t;
    part[(c * gridDim.x + blockIdx.x) * 2 + 0] = s;
    part[(c * gridDim.x + blockIdx.x) * 2 + 1] = q;
  }
}

__global__ void bn_finalize(const float* __restrict__ part,
                            const float* __restrict__ g, const float* __restrict__ b,
                            float* __restrict__ scale, float* __restrict__ shift,
                            int C, int S, float invCount) {
  int c = blockIdx.x * blockDim.x + threadIdx.x;
  if (c >= C) return;
  float sum = 0.f, sq = 0.f;
  for (int s = 0; s < S; s++) { sum += part[((size_t)c * S + s) * 2]; sq += part[((size_t)c * S + s) * 2 + 1]; }
  float m = sum * invCount;
  float var = sq * invCount - m * m;
  float sc = g[c] * rsqrtf(var + 1e-5f);
  scale[c] = sc;
  shift[c] = b[c] - m * sc;
}

// ---------------- fused BN + ReLU (+2x2 pool) + pad, fp32 -> hi/lo ---------
template<int CO, int IH, int IW, bool POOL, int PADO>
__global__ __launch_bounds__(256) void bn_act_pad_k(const float* __restrict__ x,
                                                    const float* __restrict__ scale,
                                                    const float* __restrict__ shift,
                                                    bf16* __restrict__ yh,
                                                    bf16* __restrict__ yl) {
  constexpr int OH2 = POOL ? IH / 2 : IH, OW2 = POOL ? IW / 2 : IW;
  constexpr int OHP = OH2 + 2 * PADO, OWP = OW2 + 2 * PADO;
  int i = blockIdx.x * 256 + threadIdx.x;
  if (i >= 64 * OH2 * OW2 * CO) return;
  int c = i % CO; int t = i / CO; int ow = t % OW2; t /= OW2; int oh = t % OH2; int n = t / OH2;
  float sc = scale[c], sh = shift[c];
  float v;
  if (POOL) {
    const float* p = x + (((size_t)(n * IH) + oh * 2) * IW + ow * 2) * CO + c;
    float a = p[0] * sc + sh;
    float b2 = p[CO] * sc + sh;
    float d = p[(size_t)IW * CO] * sc + sh;
    float e = p[(size_t)(IW + 1) * CO] * sc + sh;
    v = fmaxf(fmaxf(a, b2), fmaxf(d, e));
  } else {
    v = x[(size_t)i] * sc + sh;
  }
  v = fmaxf(v, 0.f);
  bf16 h, l; split2(v, h, l);
  size_t o = (((size_t)(n * OHP) + oh + PADO) * OWP + ow + PADO) * CO + c;
  yh[o] = h; yl[o] = l;
}

// ---------------- ROI SPP: feat hi/lo [64][6][16][512] -> S hi/lo ----------
__global__ __launch_bounds__(256) void spp_k(const bf16* __restrict__ fh,
                                             const bf16* __restrict__ fl,
                                             const int* __restrict__ roi,
                                             bf16* __restrict__ oh_,
                                             bf16* __restrict__ ol_) {
  int c = blockIdx.x * 256 + threadIdx.x;  // 0..511
  int r = blockIdx.y;                      // 0..255
  const int* rp = roi + r * 5;
  int im = rp[0];
  int c1 = rp[1] >> 3, r1 = rp[2] >> 3, c2 = rp[3] >> 3, r2 = rp[4] >> 3;
  int w = c2 - c1 + 1;
  int lo[6], hi[6];
  int bi = 0;
#pragma unroll
  for (int l = 1; l <= 3; l++)
    for (int k = 0; k < l; k++) {
      lo[bi] = c1 + (k * w) / l;
      hi[bi] = c1 + ((k + 1) * w + l - 1) / l - 1;
      bi++;
    }
  float mx[6];
#pragma unroll
  for (int b = 0; b < 6; b++) mx[b] = -1e30f;
  const bf16* ph = fh + (size_t)im * 96 * 512 + c;
  const bf16* pl = fl + (size_t)im * 96 * 512 + c;
  for (int row = r1; row <= r2; row++)
    for (int col = c1; col <= c2; col++) {
      size_t off = (size_t)(row * 16 + col) * 512;
      float v = (float)ph[off] + (float)pl[off];
#pragma unroll
      for (int b = 0; b < 6; b++)
        if (col >= lo[b] && col <= hi[b]) mx[b] = fmaxf(mx[b], v);
    }
  int idx[6] = {c, 512 + c * 2, 512 + c * 2 + 1, 1536 + c * 3, 1536 + c * 3 + 1, 1536 + c * 3 + 2};
#pragma unroll
  for (int b = 0; b < 6; b++) {
    bf16 h, l; split2(mx[b], h, l);
    oh_[(size_t)r * 3072 + idx[b]] = h;
    ol_[(size_t)r * 3072 + idx[b]] = l;
  }
}

// FC1: BN+ReLU, write hi/lo into CC[:, 0:2048] (ld 7936)
__global__ __launch_bounds__(256) void bn1d_apply_cc_k(const float* __restrict__ x,
                                                       const float* __restrict__ scale,
                                                       const float* __restrict__ shift,
                                                       bf16* __restrict__ ch,
                                                       bf16* __restrict__ cl) {
  int i = blockIdx.x * 256 + threadIdx.x;
  if (i >= 256 * 2048) return;
  int f = i & 2047, r = i >> 11;
  float v = fmaxf(x[i] * scale[f] + shift[f], 0.f);
  bf16 h, l; split2(v, h, l);
  ch[(size_t)r * 7936 + f] = h;
  cl[(size_t)r * 7936 + f] = l;
}

// FC2: BN+ReLU, fp32 out
__global__ __launch_bounds__(256) void bn1d_apply_f32_k(const float* __restrict__ x,
                                                        const float* __restrict__ scale,
                                                        const float* __restrict__ shift,
                                                        float* __restrict__ y) {
  int i = blockIdx.x * 256 + threadIdx.x;
  if (i >= 256 * 2048) return;
  int f = i & 2047;
  y[i] = fmaxf(x[i] * scale[f] + shift[f], 0.f);
}

// ---------------- weight transforms ----------------
template<int CI, int CO, int KS>
__global__ __launch_bounds__(256) void wconv_k(const float* __restrict__ w,
                                               bf16* __restrict__ oh_,
                                               bf16* __restrict__ ol_) {
  int i = blockIdx.x * 256 + threadIdx.x;
  if (i >= CO * KS * KS * CI) return;
  int ci = i % CI; int t = i / CI; int kw = t % KS; t /= KS; int kh = t % KS; int co = t / KS;
  float v = w[(((size_t)co * CI + ci) * KS + kh) * KS + kw];
  bf16 h, l; split2(v, h, l);
  oh_[i] = h; ol_[i] = l;
}

__global__ __launch_bounds__(256) void cast_k(const float* __restrict__ x,
                                              bf16* __restrict__ y, int n) {
  int i = blockIdx.x * 256 + threadIdx.x;
  if (i < n) y[i] = (bf16)x[i];
}

// f2w [2048][7901] fp32 -> [2048][7936] bf16 hi (zero tail)
__global__ __launch_bounds__(256) void wfc2_k(const float* __restrict__ x,
                                              bf16* __restrict__ y) {
  int i = blockIdx.x * 256 + threadIdx.x;
  if (i >= 2048 * 7936) return;
  int k = i % 7936, n = i / 7936;
  y[i] = (bf16)(k < 7901 ? x[(size_t)n * 7901 + k] : 0.f);
}

// phoc [256][5853] fp32 -> CC[:, 2048:7936] hi/lo (zero tail cols)
__global__ __launch_bounds__(256) void phoc_cc_k(const float* __restrict__ phoc,
                                                 bf16* __restrict__ ch,
                                                 bf16* __restrict__ cl) {
  int i = blockIdx.x * 256 + threadIdx.x;
  if (i >= 256 * 5888) return;
  int k = i % 5888, r = i / 5888;
  int col = 2048 + k;
  float v = (col < 7901) ? phoc[(size_t)r * 5853 + (col - 2048)] : 0.f;
  bf16 h, l; split2(v, h, l);
  ch[(size_t)r * 7936 + col] = h;
  cl[(size_t)r * 7936 + col] = l;
}

// ============================================================================
extern "C" void kernel_launch(void* const* d_in, const int* in_sizes, int n_in,
                              void* d_out, int out_size, void* d_ws, size_t ws_size,
                              hipStream_t stream) {
  (void)in_sizes; (void)n_in; (void)out_size; (void)ws_size;

  const float* x    = (const float*)d_in[0];
  const int*   roi  = (const int*)  d_in[1];
  const float* phoc = (const float*)d_in[2];
  const float* c1w  = (const float*)d_in[3];
  const float* g1   = (const float*)d_in[5];
  const float* b1   = (const float*)d_in[6];
  const float* c2w  = (const float*)d_in[7];
  const float* g2   = (const float*)d_in[9];
  const float* b2   = (const float*)d_in[10];
  const float* c3w  = (const float*)d_in[11];
  const float* g3   = (const float*)d_in[13];
  const float* b3   = (const float*)d_in[14];
  const float* c4w  = (const float*)d_in[15];
  const float* g4   = (const float*)d_in[17];
  const float* b4   = (const float*)d_in[18];
  const float* c5w  = (const float*)d_in[19];
  const float* g5   = (const float*)d_in[21];
  const float* b5   = (const float*)d_in[22];
  const float* f1w  = (const float*)d_in[23];
  const float* g6   = (const float*)d_in[25];
  const float* b6   = (const float*)d_in[26];
  const float* f2w  = (const float*)d_in[27];
  const float* g7   = (const float*)d_in[29];
  const float* b7   = (const float*)d_in[30];
  float* out = (float*)d_out;

  // ---- workspace layout (total ~167 MB) ----
  char* ws = (char*)d_ws;
  float* P    = (float*)(ws + 0x0000000);   // 1.76 MB
  bf16*  Ahi  = (bf16*) (ws + 0x0200000);   // 16 MB
  bf16*  Alo  = (bf16*) (ws + 0x1200000);   // 16 MB
  float* C    = (float*)(ws + 0x2200000);   // 51 MB
  bf16*  Wc2h = (bf16*) (ws + 0x5500000);
  bf16*  Wc3h = (bf16*) (ws + 0x5570000);
  bf16*  Wc4h = (bf16*) (ws + 0x5600000);
  bf16*  Wc5h = (bf16*) (ws + 0x5840000);
  bf16*  Wf1  = (bf16*) (ws + 0x5CC0000);
  bf16*  Wf2  = (bf16*) (ws + 0x68C0000);
  bf16*  Wc2l = (bf16*) (ws + 0x87C0000);
  bf16*  Wc3l = (bf16*) (ws + 0x8830000);
  bf16*  Wc4l = (bf16*) (ws + 0x88C0000);
  bf16*  Wc5l = (bf16*) (ws + 0x8B00000);
  bf16*  Shi  = (bf16*) (ws + 0x8F80000);   // spp out hi [256][3072]
  bf16*  Slo  = (bf16*) (ws + 0x9100000);
  float* G6   = (float*)(ws + 0x9280000);   // fc1 out fp32 [256][2048]
  bf16*  CChi = (bf16*) (ws + 0x9480000);   // concat hi [256][7936]
  bf16*  CClo = (bf16*) (ws + 0x9860000);
  float* G7   = (float*)(ws + 0x9C40000);   // fc2 out fp32 [256][2048]
  float* PART = (float*)(ws + 0x9E40000);   // 768 KB (max 128ch x 768 segs x 2)
  float* SC   = (float*)(ws + 0x9F00000);
  float* SH   = (float*)(ws + 0x9F10000);

  // ---- weight transforms ----
  wconv_k<64, 128, 5><<<800, 256, 0, stream>>>(c2w, Wc2h, Wc2l);
  wconv_k<128, 256, 3><<<1152, 256, 0, stream>>>(c3w, Wc3h, Wc3l);
  wconv_k<256, 512, 3><<<4608, 256, 0, stream>>>(c4w, Wc4h, Wc4l);
  wconv_k<512, 512, 3><<<9216, 256, 0, stream>>>(c5w, Wc5h, Wc5l);
  cast_k<<<24576, 256, 0, stream>>>(f1w, Wf1, 2048 * 3072);
  wfc2_k<<<63488, 256, 0, stream>>>(f2w, Wf2);
  phoc_cc_k<<<5888, 256, 0, stream>>>(phoc, CChi, CClo);

  // ---- conv1 (two-pass, no big fp32 buffer) ----
  pad_edge_k<<<1716, 256, 0, stream>>>(x, P);
  conv1_stats_k<<<dim3(96, 8), 256, 0, stream>>>(P, c1w, PART);
  bn_finalize<<<1, 64, 0, stream>>>(PART, g1, b1, SC, SH, 64, 96, 1.f / 393216.f);
  hipMemsetAsync(Ahi, 0, (size_t)64 * 28 * 68 * 64 * 2, stream);
  hipMemsetAsync(Alo, 0, (size_t)64 * 28 * 68 * 64 * 2, stream);
  conv1_apply_k<<<dim3(384, 8), 256, 0, stream>>>(P, c1w, SC, SH, Ahi, Alo);

  // ---- conv2: A[98304][1600] -> C[98304][128] ----
  conv_gemm_k<64, 5, 24, 64, 128, true><<<dim3(768, 1), 256, 0, stream>>>(Ahi, Alo, Wc2h, Wc2l, C, PART);
  bn_finalize<<<1, 128, 0, stream>>>(PART, g2, b2, SC, SH, 128, 768, 1.f / 98304.f);
  hipMemsetAsync(Ahi, 0, (size_t)64 * 14 * 34 * 128 * 2, stream);
  hipMemsetAsync(Alo, 0, (size_t)64 * 14 * 34 * 128 * 2, stream);
  bn_act_pad_k<128, 24, 64, true, 1><<<12288, 256, 0, stream>>>(C, SC, SH, Ahi, Alo);

  // ---- conv3 ----
  conv_gemm_k<128, 3, 12, 32, 256, true><<<dim3(192, 2), 256, 0, stream>>>(Ahi, Alo, Wc3h, Wc3l, C, PART);
  bn_finalize<<<1, 256, 0, stream>>>(PART, g3, b3, SC, SH, 256, 192, 1.f / 24576.f);
  hipMemsetAsync(Ahi, 0, (size_t)64 * 14 * 34 * 256 * 2, stream);
  hipMemsetAsync(Alo, 0, (size_t)64 * 14 * 34 * 256 * 2, stream);
  bn_act_pad_k<256, 12, 32, false, 1><<<24576, 256, 0, stream>>>(C, SC, SH, Ahi, Alo);

  // ---- conv4 ----
  conv_gemm_k<256, 3, 12, 32, 512, true><<<dim3(192, 4), 256, 0, stream>>>(Ahi, Alo, Wc4h, Wc4l, C, PART);
  bn_finalize<<<2, 256, 0, stream>>>(PART, g4, b4, SC, SH, 512, 192, 1.f / 24576.f);
  hipMemsetAsync(Ahi, 0, (size_t)64 * 8 * 18 * 512 * 2, stream);
  hipMemsetAsync(Alo, 0, (size_t)64 * 8 * 18 * 512 * 2, stream);
  bn_act_pad_k<512, 12, 32, true, 1><<<12288, 256, 0, stream>>>(C, SC, SH, Ahi, Alo);

  // ---- conv5 ----
  conv_gemm_k<512, 3, 6, 16, 512, true><<<dim3(48, 4), 256, 0, stream>>>(Ahi, Alo, Wc5h, Wc5l, C, PART);
  bn_finalize<<<2, 256, 0, stream>>>(PART, g5, b5, SC, SH, 512, 48, 1.f / 6144.f);
  bn_act_pad_k<512, 6, 16, false, 0><<<12288, 256, 0, stream>>>(C, SC, SH, Ahi, Alo);  // feat

  // ---- SPP ----
  spp_k<<<dim3(2, 256), 256, 0, stream>>>(Ahi, Alo, roi, Shi, Slo);

  // ---- FC1: [256][3072] x [2048][3072] ----
  conv_gemm_k<3072, 1, 2, 2, 2048, false><<<dim3(2, 16), 256, 0, stream>>>(Shi, Slo, Wf1, nullptr, G6, PART);
  bn_finalize<<<8, 256, 0, stream>>>(PART, g6, b6, SC, SH, 2048, 2, 1.f / 256.f);
  bn1d_apply_cc_k<<<2048, 256, 0, stream>>>(G6, SC, SH, CChi, CClo);

  // ---- FC2: [256][7936] x [2048][7936] ----
  conv_gemm_k<7936, 1, 2, 2, 2048, false><<<dim3(2, 16), 256, 0, stream>>>(CChi, CClo, Wf2, nullptr, G7, PART);
  bn_finalize<<<8, 256, 0, stream>>>(PART, g7, b7, SC, SH, 2048, 2, 1.f / 256.f);
  bn1d_apply_f32_k<<<2048, 256, 0, stream>>>(G7, SC, SH, out);
}

// Round 5
// 940.766 us; speedup vs baseline: 8.3922x; 1.2104x over previous
//
#include <hip/hip_runtime.h>
#include <hip/hip_bf16.h>

// ============================================================================
// HWNet-SPP forward, MFMA bf16 implicit-GEMM with hi/lo split precision.
// Activations stored as bf16 (hi,lo) pairs -> effectively exact A operand.
// Conv weights split hi/lo too (3-pass GEMM); FC weights hi-only (2-pass).
// BN column stats fused into GEMM epilogue (SPLIT==1) or the split-K
// reduction kernel (SPLIT>1). Conv/FC biases skipped (BN cancels them).
// ============================================================================

typedef __bf16 bf16;
using bf16x8 = __attribute__((ext_vector_type(8))) __bf16;
using f32x4  = __attribute__((ext_vector_type(4))) float;

__device__ __forceinline__ void split2(float v, bf16& h, bf16& l) {
  bf16 hb = (bf16)v;
  h = hb;
  l = (bf16)(v - (float)hb);
}

__device__ __forceinline__ void gld_lds16(const bf16* g, void* lds) {
  __builtin_amdgcn_global_load_lds(
      (const __attribute__((address_space(1))) unsigned int*)g,
      (__attribute__((address_space(3))) unsigned int*)lds, 16, 0, 0);
}

// ---------------- pad (edge mode, +2 each side of 48x128) ----------------
__global__ __launch_bounds__(256) void pad_edge_k(const float* __restrict__ x,
                                                  float* __restrict__ p) {
  int i = blockIdx.x * 256 + threadIdx.x;
  const int TOT = 64 * 52 * 132;
  if (i >= TOT) return;
  int w = i % 132; int t = i / 132; int h = t % 52; int n = t / 52;
  int sh = h - 2; sh = sh < 0 ? 0 : (sh > 47 ? 47 : sh);
  int sw = w - 2; sw = sw < 0 ? 0 : (sw > 127 ? 127 : sw);
  p[i] = x[(n * 48 + sh) * 128 + sw];
}

// ---------------- conv1 pass 1: BN stats only (fp32, recompute style) ------
__global__ __launch_bounds__(256) void conv1_stats_k(const float* __restrict__ P,
                                                     const float* __restrict__ wt,
                                                     float* __restrict__ part) {
  int co0 = blockIdx.y * 8;
  float sums[8] = {0.f}, sqs[8] = {0.f};
  for (int r = 0; r < 16; r++) {
    int pix = blockIdx.x * 4096 + r * 256 + threadIdx.x;  // 0..393215
    int w = pix & 127; int t = pix >> 7; int h = t % 48; int n = t / 48;
    const float* ip = P + ((size_t)n * 52 + h) * 132 + w;
    float win[25];
#pragma unroll
    for (int kh = 0; kh < 5; kh++)
#pragma unroll
      for (int kw = 0; kw < 5; kw++) win[kh * 5 + kw] = ip[kh * 132 + kw];
#pragma unroll
    for (int j = 0; j < 8; j++) {
      const float* wp = wt + (size_t)(co0 + j) * 25;
      float acc = 0.f;
#pragma unroll
      for (int k = 0; k < 25; k++) acc += win[k] * wp[k];
      sums[j] += acc; sqs[j] += acc * acc;
    }
  }
  __shared__ float ls[256], lq[256];
  for (int j = 0; j < 8; j++) {
    ls[threadIdx.x] = sums[j]; lq[threadIdx.x] = sqs[j];
    __syncthreads();
    for (int o = 128; o > 0; o >>= 1) {
      if (threadIdx.x < o) { ls[threadIdx.x] += ls[threadIdx.x + o]; lq[threadIdx.x] += lq[threadIdx.x + o]; }
      __syncthreads();
    }
    if (threadIdx.x == 0) {
      int c = co0 + j;
      part[((size_t)c * 96 + blockIdx.x) * 2 + 0] = ls[0];
      part[((size_t)c * 96 + blockIdx.x) * 2 + 1] = lq[0];
    }
    __syncthreads();
  }
}

// ---------------- conv1 pass 2: conv+BN+ReLU+pool+pad -> hi/lo -------------
__global__ __launch_bounds__(256) void conv1_apply_k(const float* __restrict__ P,
                                                     const float* __restrict__ wt,
                                                     const float* __restrict__ scale,
                                                     const float* __restrict__ shift,
                                                     bf16* __restrict__ yh,
                                                     bf16* __restrict__ yl) {
  int pix = blockIdx.x * 256 + threadIdx.x;  // 0..98303
  int ow = pix & 63; int t = pix >> 6; int oh = t % 24; int n = t / 24;
  int co0 = blockIdx.y * 8;
  const float* ip = P + ((size_t)n * 52 + 2 * oh) * 132 + 2 * ow;
  float win[36];
#pragma unroll
  for (int r = 0; r < 6; r++)
#pragma unroll
    for (int c = 0; c < 6; c++) win[r * 6 + c] = ip[r * 132 + c];
  bf16x8 hv, lv;
#pragma unroll
  for (int j = 0; j < 8; j++) {
    const float* wp = wt + (size_t)(co0 + j) * 25;
    float sc = scale[co0 + j], sh = shift[co0 + j];
    float m = -1e30f;
#pragma unroll
    for (int dy = 0; dy < 2; dy++)
#pragma unroll
      for (int dx = 0; dx < 2; dx++) {
        float acc = 0.f;
#pragma unroll
        for (int kh = 0; kh < 5; kh++)
#pragma unroll
          for (int kw = 0; kw < 5; kw++)
            acc += win[(kh + dy) * 6 + kw + dx] * wp[kh * 5 + kw];
        m = fmaxf(m, acc * sc + sh);
      }
    float v = fmaxf(m, 0.f);
    bf16 h, l; split2(v, h, l);
    hv[j] = h; lv[j] = l;
  }
  size_t o = (((size_t)n * 28 + oh + 2) * 68 + ow + 2) * 64 + co0;
  *(bf16x8*)(yh + o) = hv;
  *(bf16x8*)(yl + o) = lv;
}

// ---------------- MFMA implicit-GEMM with hi/lo split + optional split-K ---
// C[m,co] = (Ahi+Alo)[m,:] . (Bhi(+Blo))[co,:]
// A from padded NHWC bf16 [64][OH+KS-1][OW+KS-1][CI]; FC: KS=1,OH=OW=2.
// Tile 128x128, BK=64, 4 waves, st-swizzle via pre-swizzled source addrs.
// SPLIT==1: epilogue emits per-block per-column (sum,sumsq) partials to part.
// SPLIT>1 : blockIdx.z handles NCH/SPLIT K-chunks, writes partial slab z;
//           stats/final-C are produced by reduce_bn_k.
template<int CI, int KS, int OH, int OW, int CO, bool BLO, int SPLIT>
__global__ __launch_bounds__(256) void conv_gemm_k(const bf16* __restrict__ Ahi,
                                                   const bf16* __restrict__ Alo,
                                                   const bf16* __restrict__ Bhi,
                                                   const bf16* __restrict__ Blo,
                                                   float* __restrict__ Cout,
                                                   float* __restrict__ part) {
  static_assert(CI % 64 == 0, "chunk must not straddle ci segments");
  constexpr int K = KS * KS * CI;
  constexpr int IWP = OW + KS - 1;
  constexpr int NCH = K / 64;
  static_assert(NCH % SPLIT == 0, "split must divide chunk count");
  constexpr int NCHS = NCH / SPLIT;
  constexpr int M = 64 * OH * OW;
  __shared__ bf16 Ash[128 * 64];
  __shared__ bf16 Asl[128 * 64];
  __shared__ bf16 Bsh[128 * 64];
  __shared__ bf16 Bsl[BLO ? 128 * 64 : 64];
  __shared__ float red[2][128][8];
  const int t = threadIdx.x;
  const int lane = t & 63, w = t >> 6;
  const int m0 = blockIdx.x * 128, n0 = blockIdx.y * 128;
  const int z = (SPLIT > 1) ? blockIdx.z : 0;

  // staging source precompute: issue i covers rows (i*4+w)*8 .. +8
  int apix[4]; size_t boff[4];
#pragma unroll
  for (int i = 0; i < 4; i++) {
    int f = (i * 4 + w) * 64 + lane;
    int row = f >> 3, slot = f & 7;
    int ss = slot ^ (row & 7);               // st-swizzle on source
    int m = m0 + row;
    int n = m / (OH * OW); int rem = m % (OH * OW);
    int oh = rem / OW, ow_ = rem % OW;
    apix[i] = ((n * (OH + KS - 1) + oh) * IWP + ow_) * CI + ss * 8;
    boff[i] = (size_t)(n0 + row) * K + ss * 8;
  }

  // ds_read fragment addresses
  const int wrow = w >> 1, wcol = w & 1;
  const int kg = lane >> 4;
  int arb[4], amk[4], brb[4], bmk[4];
#pragma unroll
  for (int q = 0; q < 4; q++) {
    int ra = wrow * 64 + q * 16 + (lane & 15);
    arb[q] = ra * 128; amk[q] = ra & 7;
    int rb = wcol * 64 + q * 16 + (lane & 15);
    brb[q] = rb * 128; bmk[q] = rb & 7;
  }
  const char* Ashb = (const char*)Ash;
  const char* Aslb = (const char*)Asl;
  const char* Bshb = (const char*)Bsh;
  const char* Bslb = (const char*)Bsl;

  f32x4 acc[4][4] = {};
  for (int kc = z * NCHS; kc < (z + 1) * NCHS; ++kc) {
    const int k0 = kc * 64;
    const int seg = k0 / CI;
    const int ci0 = k0 % CI;
    const int kh = seg / KS, kw = seg % KS;
    const int aoff = (kh * IWP + kw) * CI + ci0;   // wave-uniform
#pragma unroll
    for (int i = 0; i < 4; i++) {
      gld_lds16(Ahi + (size_t)apix[i] + aoff, (char*)Ash + (i * 4 + w) * 1024);
      gld_lds16(Alo + (size_t)apix[i] + aoff, (char*)Asl + (i * 4 + w) * 1024);
      gld_lds16(Bhi + boff[i] + k0,           (char*)Bsh + (i * 4 + w) * 1024);
      if (BLO)
        gld_lds16(Blo + boff[i] + k0,         (char*)Bsl + (i * 4 + w) * 1024);
    }
    __syncthreads();
#pragma unroll
    for (int ks = 0; ks < 2; ks++) {
      const int slot = ks * 4 + kg;
      bf16x8 ah[4], al[4], bh[4];
#pragma unroll
      for (int q = 0; q < 4; q++) {
        ah[q] = *(const bf16x8*)(Ashb + arb[q] + ((slot ^ amk[q]) << 4));
        al[q] = *(const bf16x8*)(Aslb + arb[q] + ((slot ^ amk[q]) << 4));
        bh[q] = *(const bf16x8*)(Bshb + brb[q] + ((slot ^ bmk[q]) << 4));
      }
#pragma unroll
      for (int mi = 0; mi < 4; mi++)
#pragma unroll
        for (int ni = 0; ni < 4; ni++)
          acc[mi][ni] = __builtin_amdgcn_mfma_f32_16x16x32_bf16(ah[mi], bh[ni], acc[mi][ni], 0, 0, 0);
#pragma unroll
      for (int mi = 0; mi < 4; mi++)
#pragma unroll
        for (int ni = 0; ni < 4; ni++)
          acc[mi][ni] = __builtin_amdgcn_mfma_f32_16x16x32_bf16(al[mi], bh[ni], acc[mi][ni], 0, 0, 0);
      if (BLO) {
        bf16x8 bl[4];
#pragma unroll
        for (int q = 0; q < 4; q++)
          bl[q] = *(const bf16x8*)(Bslb + brb[q] + ((slot ^ bmk[q]) << 4));
#pragma unroll
        for (int mi = 0; mi < 4; mi++)
#pragma unroll
          for (int ni = 0; ni < 4; ni++)
            acc[mi][ni] = __builtin_amdgcn_mfma_f32_16x16x32_bf16(ah[mi], bl[ni], acc[mi][ni], 0, 0, 0);
      }
    }
    __syncthreads();
  }

  // epilogue: D row = (lane>>4)*4 + jj, col = lane&15
  const int crow0 = (lane >> 4) * 4, ccol = lane & 15;
  float* Cz = Cout + (size_t)z * M * CO;
#pragma unroll
  for (int mi = 0; mi < 4; mi++) {
    int m = m0 + wrow * 64 + mi * 16 + crow0;
#pragma unroll
    for (int ni = 0; ni < 4; ni++) {
      int nn = n0 + wcol * 64 + ni * 16 + ccol;
      float* cp = Cz + (size_t)m * CO + nn;
#pragma unroll
      for (int jj = 0; jj < 4; jj++) cp[(size_t)jj * CO] = acc[mi][ni][jj];
    }
  }
  if constexpr (SPLIT == 1) {
    // fused BN partials: per-thread 16-row sums per owned column
    const int contrib = kg * 2 + wrow;  // 8 contributors per column
#pragma unroll
    for (int ni = 0; ni < 4; ni++) {
      float s = 0.f, q = 0.f;
#pragma unroll
      for (int mi = 0; mi < 4; mi++)
#pragma unroll
        for (int jj = 0; jj < 4; jj++) {
          float v = acc[mi][ni][jj];
          s += v; q += v * v;
        }
      int coll = wcol * 64 + ni * 16 + ccol;
      red[0][coll][contrib] = s;
      red[1][coll][contrib] = q;
    }
    __syncthreads();
    if (t < 128) {
      float s = 0.f, q = 0.f;
#pragma unroll
      for (int j = 0; j < 8; j++) { s += red[0][t][j]; q += red[1][t][j]; }
      size_t c = n0 + t;
      part[(c * gridDim.x + blockIdx.x) * 2 + 0] = s;
      part[(c * gridDim.x + blockIdx.x) * 2 + 1] = q;
    }
  }
}

// ---------------- split-K reduction + BN partials ----------------
// Cp: SPLIT slabs of [M][CO] fp32. Cf: final [M][CO]. part: [CO][NS][2].
// grid (CO/64, NS), 256 threads = 64 cols x 4 row-lanes.
template<int M, int CO, int SPLIT, int NS>
__global__ __launch_bounds__(256) void reduce_bn_k(const float* __restrict__ Cp,
                                                   float* __restrict__ Cf,
                                                   float* __restrict__ part) {
  int c = blockIdx.x * 64 + (threadIdx.x & 63);
  int rl = threadIdx.x >> 6;
  constexpr int ROWS = M / NS;
  int r0 = blockIdx.y * ROWS;
  float sum = 0.f, sq = 0.f;
  for (int r = r0 + rl; r < r0 + ROWS; r += 4) {
    float v = 0.f;
#pragma unroll
    for (int s = 0; s < SPLIT; s++) v += Cp[(size_t)s * M * CO + (size_t)r * CO + c];
    Cf[(size_t)r * CO + c] = v;
    sum += v; sq += v * v;
  }
  __shared__ float ls[256], lq[256];
  ls[threadIdx.x] = sum; lq[threadIdx.x] = sq;
  __syncthreads();
  if (threadIdx.x < 64) {
    sum = ls[threadIdx.x] + ls[threadIdx.x + 64] + ls[threadIdx.x + 128] + ls[threadIdx.x + 192];
    sq  = lq[threadIdx.x] + lq[threadIdx.x + 64] + lq[threadIdx.x + 128] + lq[threadIdx.x + 192];
    part[((size_t)c * NS + blockIdx.y) * 2 + 0] = sum;
    part[((size_t)c * NS + blockIdx.y) * 2 + 1] = sq;
  }
}

__global__ void bn_finalize(const float* __restrict__ part,
                            const float* __restrict__ g, const float* __restrict__ b,
                            float* __restrict__ scale, float* __restrict__ shift,
                            int C, int S, float invCount) {
  int c = blockIdx.x * blockDim.x + threadIdx.x;
  if (c >= C) return;
  float sum = 0.f, sq = 0.f;
  for (int s = 0; s < S; s++) { sum += part[((size_t)c * S + s) * 2]; sq += part[((size_t)c * S + s) * 2 + 1]; }
  float m = sum * invCount;
  float var = sq * invCount - m * m;
  float sc = g[c] * rsqrtf(var + 1e-5f);
  scale[c] = sc;
  shift[c] = b[c] - m * sc;
}

// ---------------- fused BN + ReLU (+2x2 pool) + pad, fp32 -> hi/lo ---------
template<int CO, int IH, int IW, bool POOL, int PADO>
__global__ __launch_bounds__(256) void bn_act_pad_k(const float* __restrict__ x,
                                                    const float* __restrict__ scale,
                                                    const float* __restrict__ shift,
                                                    bf16* __restrict__ yh,
                                                    bf16* __restrict__ yl) {
  constexpr int OH2 = POOL ? IH / 2 : IH, OW2 = POOL ? IW / 2 : IW;
  constexpr int OHP = OH2 + 2 * PADO, OWP = OW2 + 2 * PADO;
  int i = blockIdx.x * 256 + threadIdx.x;
  if (i >= 64 * OH2 * OW2 * CO) return;
  int c = i % CO; int t = i / CO; int ow = t % OW2; t /= OW2; int oh = t % OH2; int n = t / OH2;
  float sc = scale[c], sh = shift[c];
  float v;
  if (POOL) {
    const float* p = x + (((size_t)(n * IH) + oh * 2) * IW + ow * 2) * CO + c;
    float a = p[0] * sc + sh;
    float b2 = p[CO] * sc + sh;
    float d = p[(size_t)IW * CO] * sc + sh;
    float e = p[(size_t)(IW + 1) * CO] * sc + sh;
    v = fmaxf(fmaxf(a, b2), fmaxf(d, e));
  } else {
    v = x[(size_t)i] * sc + sh;
  }
  v = fmaxf(v, 0.f);
  bf16 h, l; split2(v, h, l);
  size_t o = (((size_t)(n * OHP) + oh + PADO) * OWP + ow + PADO) * CO + c;
  yh[o] = h; yl[o] = l;
}

// ---------------- ROI SPP: feat hi/lo [64][6][16][512] -> S hi/lo ----------
__global__ __launch_bounds__(256) void spp_k(const bf16* __restrict__ fh,
                                             const bf16* __restrict__ fl,
                                             const int* __restrict__ roi,
                                             bf16* __restrict__ oh_,
                                             bf16* __restrict__ ol_) {
  int c = blockIdx.x * 256 + threadIdx.x;  // 0..511
  int r = blockIdx.y;                      // 0..255
  const int* rp = roi + r * 5;
  int im = rp[0];
  int c1 = rp[1] >> 3, r1 = rp[2] >> 3, c2 = rp[3] >> 3, r2 = rp[4] >> 3;
  int w = c2 - c1 + 1;
  int lo[6], hi[6];
  int bi = 0;
#pragma unroll
  for (int l = 1; l <= 3; l++)
    for (int k = 0; k < l; k++) {
      lo[bi] = c1 + (k * w) / l;
      hi[bi] = c1 + ((k + 1) * w + l - 1) / l - 1;
      bi++;
    }
  float mx[6];
#pragma unroll
  for (int b = 0; b < 6; b++) mx[b] = -1e30f;
  const bf16* ph = fh + (size_t)im * 96 * 512 + c;
  const bf16* pl = fl + (size_t)im * 96 * 512 + c;
  for (int row = r1; row <= r2; row++)
    for (int col = c1; col <= c2; col++) {
      size_t off = (size_t)(row * 16 + col) * 512;
      float v = (float)ph[off] + (float)pl[off];
#pragma unroll
      for (int b = 0; b < 6; b++)
        if (col >= lo[b] && col <= hi[b]) mx[b] = fmaxf(mx[b], v);
    }
  int idx[6] = {c, 512 + c * 2, 512 + c * 2 + 1, 1536 + c * 3, 1536 + c * 3 + 1, 1536 + c * 3 + 2};
#pragma unroll
  for (int b = 0; b < 6; b++) {
    bf16 h, l; split2(mx[b], h, l);
    oh_[(size_t)r * 3072 + idx[b]] = h;
    ol_[(size_t)r * 3072 + idx[b]] = l;
  }
}

// FC1: BN+ReLU, write hi/lo into CC[:, 0:2048] (ld 7936)
__global__ __launch_bounds__(256) void bn1d_apply_cc_k(const float* __restrict__ x,
                                                       const float* __restrict__ scale,
                                                       const float* __restrict__ shift,
                                                       bf16* __restrict__ ch,
                                                       bf16* __restrict__ cl) {
  int i = blockIdx.x * 256 + threadIdx.x;
  if (i >= 256 * 2048) return;
  int f = i & 2047, r = i >> 11;
  float v = fmaxf(x[i] * scale[f] + shift[f], 0.f);
  bf16 h, l; split2(v, h, l);
  ch[(size_t)r * 7936 + f] = h;
  cl[(size_t)r * 7936 + f] = l;
}

// FC2: BN+ReLU, fp32 out
__global__ __launch_bounds__(256) void bn1d_apply_f32_k(const float* __restrict__ x,
                                                        const float* __restrict__ scale,
                                                        const float* __restrict__ shift,
                                                        float* __restrict__ y) {
  int i = blockIdx.x * 256 + threadIdx.x;
  if (i >= 256 * 2048) return;
  int f = i & 2047;
  y[i] = fmaxf(x[i] * scale[f] + shift[f], 0.f);
}

// ---------------- weight transforms ----------------
template<int CI, int CO, int KS>
__global__ __launch_bounds__(256) void wconv_k(const float* __restrict__ w,
                                               bf16* __restrict__ oh_,
                                               bf16* __restrict__ ol_) {
  int i = blockIdx.x * 256 + threadIdx.x;
  if (i >= CO * KS * KS * CI) return;
  int ci = i % CI; int t = i / CI; int kw = t % KS; t /= KS; int kh = t % KS; int co = t / KS;
  float v = w[(((size_t)co * CI + ci) * KS + kh) * KS + kw];
  bf16 h, l; split2(v, h, l);
  oh_[i] = h; ol_[i] = l;
}

__global__ __launch_bounds__(256) void cast_k(const float* __restrict__ x,
                                              bf16* __restrict__ y, int n) {
  int i = blockIdx.x * 256 + threadIdx.x;
  if (i < n) y[i] = (bf16)x[i];
}

// f2w [2048][7901] fp32 -> [2048][7936] bf16 hi (zero tail)
__global__ __launch_bounds__(256) void wfc2_k(const float* __restrict__ x,
                                              bf16* __restrict__ y) {
  int i = blockIdx.x * 256 + threadIdx.x;
  if (i >= 2048 * 7936) return;
  int k = i % 7936, n = i / 7936;
  y[i] = (bf16)(k < 7901 ? x[(size_t)n * 7901 + k] : 0.f);
}

// phoc [256][5853] fp32 -> CC[:, 2048:7936] hi/lo (zero tail cols)
__global__ __launch_bounds__(256) void phoc_cc_k(const float* __restrict__ phoc,
                                                 bf16* __restrict__ ch,
                                                 bf16* __restrict__ cl) {
  int i = blockIdx.x * 256 + threadIdx.x;
  if (i >= 256 * 5888) return;
  int k = i % 5888, r = i / 5888;
  int col = 2048 + k;
  float v = (col < 7901) ? phoc[(size_t)r * 5853 + (col - 2048)] : 0.f;
  bf16 h, l; split2(v, h, l);
  ch[(size_t)r * 7936 + col] = h;
  cl[(size_t)r * 7936 + col] = l;
}

// ============================================================================
extern "C" void kernel_launch(void* const* d_in, const int* in_sizes, int n_in,
                              void* d_out, int out_size, void* d_ws, size_t ws_size,
                              hipStream_t stream) {
  (void)in_sizes; (void)n_in; (void)out_size; (void)ws_size;

  const float* x    = (const float*)d_in[0];
  const int*   roi  = (const int*)  d_in[1];
  const float* phoc = (const float*)d_in[2];
  const float* c1w  = (const float*)d_in[3];
  const float* g1   = (const float*)d_in[5];
  const float* b1   = (const float*)d_in[6];
  const float* c2w  = (const float*)d_in[7];
  const float* g2   = (const float*)d_in[9];
  const float* b2   = (const float*)d_in[10];
  const float* c3w  = (const float*)d_in[11];
  const float* g3   = (const float*)d_in[13];
  const float* b3   = (const float*)d_in[14];
  const float* c4w  = (const float*)d_in[15];
  const float* g4   = (const float*)d_in[17];
  const float* b4   = (const float*)d_in[18];
  const float* c5w  = (const float*)d_in[19];
  const float* g5   = (const float*)d_in[21];
  const float* b5   = (const float*)d_in[22];
  const float* f1w  = (const float*)d_in[23];
  const float* g6   = (const float*)d_in[25];
  const float* b6   = (const float*)d_in[26];
  const float* f2w  = (const float*)d_in[27];
  const float* g7   = (const float*)d_in[29];
  const float* b7   = (const float*)d_in[30];
  float* out = (float*)d_out;

  // ---- workspace layout (total ~167 MB) ----
  char* ws = (char*)d_ws;
  float* P    = (float*)(ws + 0x0000000);   // 1.76 MB
  bf16*  Ahi  = (bf16*) (ws + 0x0200000);   // 16 MB
  bf16*  Alo  = (bf16*) (ws + 0x1200000);   // 16 MB
  float* C    = (float*)(ws + 0x2200000);   // 51 MB region (GEMM out / split slabs)
  float* C5F  = (float*)(ws + 0x4200000);   // conv5 final (32MB into C region)
  bf16*  Wc2h = (bf16*) (ws + 0x5500000);
  bf16*  Wc3h = (bf16*) (ws + 0x5570000);
  bf16*  Wc4h = (bf16*) (ws + 0x5600000);
  bf16*  Wc5h = (bf16*) (ws + 0x5840000);
  bf16*  Wf1  = (bf16*) (ws + 0x5CC0000);
  bf16*  Wf2  = (bf16*) (ws + 0x68C0000);
  bf16*  Wc2l = (bf16*) (ws + 0x87C0000);
  bf16*  Wc3l = (bf16*) (ws + 0x8830000);
  bf16*  Wc4l = (bf16*) (ws + 0x88C0000);
  bf16*  Wc5l = (bf16*) (ws + 0x8B00000);
  bf16*  Shi  = (bf16*) (ws + 0x8F80000);   // spp out hi [256][3072]
  bf16*  Slo  = (bf16*) (ws + 0x9100000);
  float* G6   = (float*)(ws + 0x9280000);   // fc1 out fp32 [256][2048]
  bf16*  CChi = (bf16*) (ws + 0x9480000);   // concat hi [256][7936]
  bf16*  CClo = (bf16*) (ws + 0x9860000);
  float* G7   = (float*)(ws + 0x9C40000);   // fc2 out fp32 [256][2048]
  float* PART = (float*)(ws + 0x9E40000);   // 768 KB
  float* SC   = (float*)(ws + 0x9F00000);
  float* SH   = (float*)(ws + 0x9F10000);

  // ---- weight transforms ----
  wconv_k<64, 128, 5><<<800, 256, 0, stream>>>(c2w, Wc2h, Wc2l);
  wconv_k<128, 256, 3><<<1152, 256, 0, stream>>>(c3w, Wc3h, Wc3l);
  wconv_k<256, 512, 3><<<4608, 256, 0, stream>>>(c4w, Wc4h, Wc4l);
  wconv_k<512, 512, 3><<<9216, 256, 0, stream>>>(c5w, Wc5h, Wc5l);
  cast_k<<<24576, 256, 0, stream>>>(f1w, Wf1, 2048 * 3072);
  wfc2_k<<<63488, 256, 0, stream>>>(f2w, Wf2);
  phoc_cc_k<<<5888, 256, 0, stream>>>(phoc, CChi, CClo);

  // ---- conv1 (two-pass, no big fp32 buffer) ----
  pad_edge_k<<<1716, 256, 0, stream>>>(x, P);
  conv1_stats_k<<<dim3(96, 8), 256, 0, stream>>>(P, c1w, PART);
  bn_finalize<<<1, 64, 0, stream>>>(PART, g1, b1, SC, SH, 64, 96, 1.f / 393216.f);
  hipMemsetAsync(Ahi, 0, (size_t)64 * 28 * 68 * 64 * 2, stream);
  hipMemsetAsync(Alo, 0, (size_t)64 * 28 * 68 * 64 * 2, stream);
  conv1_apply_k<<<dim3(384, 8), 256, 0, stream>>>(P, c1w, SC, SH, Ahi, Alo);

  // ---- conv2: A[98304][1600] -> C[98304][128] ----
  conv_gemm_k<64, 5, 24, 64, 128, true, 1><<<dim3(768, 1), 256, 0, stream>>>(Ahi, Alo, Wc2h, Wc2l, C, PART);
  bn_finalize<<<1, 128, 0, stream>>>(PART, g2, b2, SC, SH, 128, 768, 1.f / 98304.f);
  hipMemsetAsync(Ahi, 0, (size_t)64 * 14 * 34 * 128 * 2, stream);
  hipMemsetAsync(Alo, 0, (size_t)64 * 14 * 34 * 128 * 2, stream);
  bn_act_pad_k<128, 24, 64, true, 1><<<12288, 256, 0, stream>>>(C, SC, SH, Ahi, Alo);

  // ---- conv3 ----
  conv_gemm_k<128, 3, 12, 32, 256, true, 1><<<dim3(192, 2), 256, 0, stream>>>(Ahi, Alo, Wc3h, Wc3l, C, PART);
  bn_finalize<<<1, 256, 0, stream>>>(PART, g3, b3, SC, SH, 256, 192, 1.f / 24576.f);
  hipMemsetAsync(Ahi, 0, (size_t)64 * 14 * 34 * 256 * 2, stream);
  hipMemsetAsync(Alo, 0, (size_t)64 * 14 * 34 * 256 * 2, stream);
  bn_act_pad_k<256, 12, 32, false, 1><<<24576, 256, 0, stream>>>(C, SC, SH, Ahi, Alo);

  // ---- conv4 ----
  conv_gemm_k<256, 3, 12, 32, 512, true, 1><<<dim3(192, 4), 256, 0, stream>>>(Ahi, Alo, Wc4h, Wc4l, C, PART);
  bn_finalize<<<2, 256, 0, stream>>>(PART, g4, b4, SC, SH, 512, 192, 1.f / 24576.f);
  hipMemsetAsync(Ahi, 0, (size_t)64 * 8 * 18 * 512 * 2, stream);
  hipMemsetAsync(Alo, 0, (size_t)64 * 8 * 18 * 512 * 2, stream);
  bn_act_pad_k<512, 12, 32, true, 1><<<12288, 256, 0, stream>>>(C, SC, SH, Ahi, Alo);

  // ---- conv5 (split-K=2): partial slabs in C, final in C5F ----
  conv_gemm_k<512, 3, 6, 16, 512, true, 2><<<dim3(48, 4, 2), 256, 0, stream>>>(Ahi, Alo, Wc5h, Wc5l, C, nullptr);
  reduce_bn_k<6144, 512, 2, 16><<<dim3(8, 16), 256, 0, stream>>>(C, C5F, PART);
  bn_finalize<<<2, 256, 0, stream>>>(PART, g5, b5, SC, SH, 512, 16, 1.f / 6144.f);
  bn_act_pad_k<512, 6, 16, false, 0><<<12288, 256, 0, stream>>>(C5F, SC, SH, Ahi, Alo);  // feat

  // ---- SPP ----
  spp_k<<<dim3(2, 256), 256, 0, stream>>>(Ahi, Alo, roi, Shi, Slo);

  // ---- FC1 (split-K=4): [256][3072] x [2048][3072] ----
  conv_gemm_k<3072, 1, 2, 2, 2048, false, 4><<<dim3(2, 16, 4), 256, 0, stream>>>(Shi, Slo, Wf1, nullptr, C, nullptr);
  reduce_bn_k<256, 2048, 4, 4><<<dim3(32, 4), 256, 0, stream>>>(C, G6, PART);
  bn_finalize<<<8, 256, 0, stream>>>(PART, g6, b6, SC, SH, 2048, 4, 1.f / 256.f);
  bn1d_apply_cc_k<<<2048, 256, 0, stream>>>(G6, SC, SH, CChi, CClo);

  // ---- FC2 (split-K=4): [256][7936] x [2048][7936] ----
  conv_gemm_k<7936, 1, 2, 2, 2048, false, 4><<<dim3(2, 16, 4), 256, 0, stream>>>(CChi, CClo, Wf2, nullptr, C, nullptr);
  reduce_bn_k<256, 2048, 4, 4><<<dim3(32, 4), 256, 0, stream>>>(C, G7, PART);
  bn_finalize<<<8, 256, 0, stream>>>(PART, g7, b7, SC, SH, 2048, 4, 1.f / 256.f);
  bn1d_apply_f32_k<<<2048, 256, 0, stream>>>(G7, SC, SH, out);
}

// Round 6
// 820.362 us; speedup vs baseline: 9.6239x; 1.1468x over previous
//
#include <hip/hip_runtime.h>
#include <hip/hip_bf16.h>

// ============================================================================
// HWNet-SPP forward, MFMA bf16 implicit-GEMM with hi/lo split precision.
// Activations stored as bf16 (hi,lo) pairs -> effectively exact A operand.
// conv3/conv5 weights split hi/lo (3-pass GEMM); conv2/conv4 + FC weights
// hi-only (2-pass). BN column stats fused into GEMM epilogue (SPLIT==1) or
// the split-K reduction kernel (SPLIT>1). Conv/FC biases skipped (BN
// mean-subtraction cancels them exactly). Halo zeros written by epilogues.
// ============================================================================

typedef __bf16 bf16;
using bf16x8 = __attribute__((ext_vector_type(8))) __bf16;
using f32x4  = __attribute__((ext_vector_type(4))) float;

__device__ __forceinline__ void split2(float v, bf16& h, bf16& l) {
  bf16 hb = (bf16)v;
  h = hb;
  l = (bf16)(v - (float)hb);
}

__device__ __forceinline__ void gld_lds16(const bf16* g, void* lds) {
  __builtin_amdgcn_global_load_lds(
      (const __attribute__((address_space(1))) unsigned int*)g,
      (__attribute__((address_space(3))) unsigned int*)lds, 16, 0, 0);
}

// ---------------- pad (edge mode, +2 each side of 48x128) ----------------
__global__ __launch_bounds__(256) void pad_edge_k(const float* __restrict__ x,
                                                  float* __restrict__ p) {
  int i = blockIdx.x * 256 + threadIdx.x;
  const int TOT = 64 * 52 * 132;
  if (i >= TOT) return;
  int w = i % 132; int t = i / 132; int h = t % 52; int n = t / 52;
  int sh = h - 2; sh = sh < 0 ? 0 : (sh > 47 ? 47 : sh);
  int sw = w - 2; sw = sw < 0 ? 0 : (sw > 127 ? 127 : sw);
  p[i] = x[(n * 48 + sh) * 128 + sw];
}

// ---------------- conv1 pass 1: BN stats only (fp32, recompute style) ------
__global__ __launch_bounds__(256) void conv1_stats_k(const float* __restrict__ P,
                                                     const float* __restrict__ wt,
                                                     float* __restrict__ part) {
  int co0 = blockIdx.y * 8;
  float sums[8] = {0.f}, sqs[8] = {0.f};
  for (int r = 0; r < 16; r++) {
    int pix = blockIdx.x * 4096 + r * 256 + threadIdx.x;  // 0..393215
    int w = pix & 127; int t = pix >> 7; int h = t % 48; int n = t / 48;
    const float* ip = P + ((size_t)n * 52 + h) * 132 + w;
    float win[25];
#pragma unroll
    for (int kh = 0; kh < 5; kh++)
#pragma unroll
      for (int kw = 0; kw < 5; kw++) win[kh * 5 + kw] = ip[kh * 132 + kw];
#pragma unroll
    for (int j = 0; j < 8; j++) {
      const float* wp = wt + (size_t)(co0 + j) * 25;
      float acc = 0.f;
#pragma unroll
      for (int k = 0; k < 25; k++) acc += win[k] * wp[k];
      sums[j] += acc; sqs[j] += acc * acc;
    }
  }
  __shared__ float ls[256], lq[256];
  for (int j = 0; j < 8; j++) {
    ls[threadIdx.x] = sums[j]; lq[threadIdx.x] = sqs[j];
    __syncthreads();
    for (int o = 128; o > 0; o >>= 1) {
      if (threadIdx.x < o) { ls[threadIdx.x] += ls[threadIdx.x + o]; lq[threadIdx.x] += lq[threadIdx.x + o]; }
      __syncthreads();
    }
    if (threadIdx.x == 0) {
      int c = co0 + j;
      part[((size_t)c * 96 + blockIdx.x) * 2 + 0] = ls[0];
      part[((size_t)c * 96 + blockIdx.x) * 2 + 1] = lq[0];
    }
    __syncthreads();
  }
}

// ---------------- conv1 pass 2: conv+BN+ReLU+pool+pad -> hi/lo -------------
__global__ __launch_bounds__(256) void conv1_apply_k(const float* __restrict__ P,
                                                     const float* __restrict__ wt,
                                                     const float* __restrict__ scale,
                                                     const float* __restrict__ shift,
                                                     bf16* __restrict__ yh,
                                                     bf16* __restrict__ yl) {
  int pix = blockIdx.x * 256 + threadIdx.x;  // 0..98303
  int ow = pix & 63; int t = pix >> 6; int oh = t % 24; int n = t / 24;
  int co0 = blockIdx.y * 8;
  const float* ip = P + ((size_t)n * 52 + 2 * oh) * 132 + 2 * ow;
  float win[36];
#pragma unroll
  for (int r = 0; r < 6; r++)
#pragma unroll
    for (int c = 0; c < 6; c++) win[r * 6 + c] = ip[r * 132 + c];
  bf16x8 hv, lv;
#pragma unroll
  for (int j = 0; j < 8; j++) {
    const float* wp = wt + (size_t)(co0 + j) * 25;
    float sc = scale[co0 + j], sh = shift[co0 + j];
    float m = -1e30f;
#pragma unroll
    for (int dy = 0; dy < 2; dy++)
#pragma unroll
      for (int dx = 0; dx < 2; dx++) {
        float acc = 0.f;
#pragma unroll
        for (int kh = 0; kh < 5; kh++)
#pragma unroll
          for (int kw = 0; kw < 5; kw++)
            acc += win[(kh + dy) * 6 + kw + dx] * wp[kh * 5 + kw];
        m = fmaxf(m, acc * sc + sh);
      }
    float v = fmaxf(m, 0.f);
    bf16 h, l; split2(v, h, l);
    hv[j] = h; lv[j] = l;
  }
  size_t o = (((size_t)n * 28 + oh + 2) * 68 + ow + 2) * 64 + co0;
  *(bf16x8*)(yh + o) = hv;
  *(bf16x8*)(yl + o) = lv;
}

// ---------------- MFMA implicit-GEMM with hi/lo split + optional split-K ---
// C[m,co] = (Ahi+Alo)[m,:] . (Bhi(+Blo))[co,:]
// A from padded NHWC bf16 [64][OH+KS-1][OW+KS-1][CI]; FC: KS=1,OH=OW=2.
// Tile 128x128, BK=64, 4 waves, st-swizzle via pre-swizzled source addrs.
// SPLIT==1: epilogue emits per-block per-column (sum,sumsq) partials to part.
// SPLIT>1 : blockIdx.z handles NCH/SPLIT K-chunks, writes partial slab z.
template<int CI, int KS, int OH, int OW, int CO, bool BLO, int SPLIT>
__global__ __launch_bounds__(256) void conv_gemm_k(const bf16* __restrict__ Ahi,
                                                   const bf16* __restrict__ Alo,
                                                   const bf16* __restrict__ Bhi,
                                                   const bf16* __restrict__ Blo,
                                                   float* __restrict__ Cout,
                                                   float* __restrict__ part) {
  static_assert(CI % 64 == 0, "chunk must not straddle ci segments");
  constexpr int K = KS * KS * CI;
  constexpr int IWP = OW + KS - 1;
  constexpr int NCH = K / 64;
  static_assert(NCH % SPLIT == 0, "split must divide chunk count");
  constexpr int NCHS = NCH / SPLIT;
  constexpr int M = 64 * OH * OW;
  __shared__ bf16 Ash[128 * 64];
  __shared__ bf16 Asl[128 * 64];
  __shared__ bf16 Bsh[128 * 64];
  __shared__ bf16 Bsl[BLO ? 128 * 64 : 64];
  __shared__ float red[2][128][8];
  const int t = threadIdx.x;
  const int lane = t & 63, w = t >> 6;
  const int m0 = blockIdx.x * 128, n0 = blockIdx.y * 128;
  const int z = (SPLIT > 1) ? blockIdx.z : 0;

  // staging source precompute: issue i covers rows (i*4+w)*8 .. +8
  int apix[4]; size_t boff[4];
#pragma unroll
  for (int i = 0; i < 4; i++) {
    int f = (i * 4 + w) * 64 + lane;
    int row = f >> 3, slot = f & 7;
    int ss = slot ^ (row & 7);               // st-swizzle on source
    int m = m0 + row;
    int n = m / (OH * OW); int rem = m % (OH * OW);
    int oh = rem / OW, ow_ = rem % OW;
    apix[i] = ((n * (OH + KS - 1) + oh) * IWP + ow_) * CI + ss * 8;
    boff[i] = (size_t)(n0 + row) * K + ss * 8;
  }

  // ds_read fragment addresses
  const int wrow = w >> 1, wcol = w & 1;
  const int kg = lane >> 4;
  int arb[4], amk[4], brb[4], bmk[4];
#pragma unroll
  for (int q = 0; q < 4; q++) {
    int ra = wrow * 64 + q * 16 + (lane & 15);
    arb[q] = ra * 128; amk[q] = ra & 7;
    int rb = wcol * 64 + q * 16 + (lane & 15);
    brb[q] = rb * 128; bmk[q] = rb & 7;
  }
  const char* Ashb = (const char*)Ash;
  const char* Aslb = (const char*)Asl;
  const char* Bshb = (const char*)Bsh;
  const char* Bslb = (const char*)Bsl;

  f32x4 acc[4][4] = {};
  for (int kc = z * NCHS; kc < (z + 1) * NCHS; ++kc) {
    const int k0 = kc * 64;
    const int seg = k0 / CI;
    const int ci0 = k0 % CI;
    const int kh = seg / KS, kw = seg % KS;
    const int aoff = (kh * IWP + kw) * CI + ci0;   // wave-uniform
#pragma unroll
    for (int i = 0; i < 4; i++) {
      gld_lds16(Ahi + (size_t)apix[i] + aoff, (char*)Ash + (i * 4 + w) * 1024);
      gld_lds16(Alo + (size_t)apix[i] + aoff, (char*)Asl + (i * 4 + w) * 1024);
      gld_lds16(Bhi + boff[i] + k0,           (char*)Bsh + (i * 4 + w) * 1024);
      if (BLO)
        gld_lds16(Blo + boff[i] + k0,         (char*)Bsl + (i * 4 + w) * 1024);
    }
    __syncthreads();
#pragma unroll
    for (int ks = 0; ks < 2; ks++) {
      const int slot = ks * 4 + kg;
      bf16x8 ah[4], al[4], bh[4];
#pragma unroll
      for (int q = 0; q < 4; q++) {
        ah[q] = *(const bf16x8*)(Ashb + arb[q] + ((slot ^ amk[q]) << 4));
        al[q] = *(const bf16x8*)(Aslb + arb[q] + ((slot ^ amk[q]) << 4));
        bh[q] = *(const bf16x8*)(Bshb + brb[q] + ((slot ^ bmk[q]) << 4));
      }
#pragma unroll
      for (int mi = 0; mi < 4; mi++)
#pragma unroll
        for (int ni = 0; ni < 4; ni++)
          acc[mi][ni] = __builtin_amdgcn_mfma_f32_16x16x32_bf16(ah[mi], bh[ni], acc[mi][ni], 0, 0, 0);
#pragma unroll
      for (int mi = 0; mi < 4; mi++)
#pragma unroll
        for (int ni = 0; ni < 4; ni++)
          acc[mi][ni] = __builtin_amdgcn_mfma_f32_16x16x32_bf16(al[mi], bh[ni], acc[mi][ni], 0, 0, 0);
      if (BLO) {
        bf16x8 bl[4];
#pragma unroll
        for (int q = 0; q < 4; q++)
          bl[q] = *(const bf16x8*)(Bslb + brb[q] + ((slot ^ bmk[q]) << 4));
#pragma unroll
        for (int mi = 0; mi < 4; mi++)
#pragma unroll
          for (int ni = 0; ni < 4; ni++)
            acc[mi][ni] = __builtin_amdgcn_mfma_f32_16x16x32_bf16(ah[mi], bl[ni], acc[mi][ni], 0, 0, 0);
      }
    }
    __syncthreads();
  }

  // epilogue: D row = (lane>>4)*4 + jj, col = lane&15
  const int crow0 = (lane >> 4) * 4, ccol = lane & 15;
  float* Cz = Cout + (size_t)z * M * CO;
#pragma unroll
  for (int mi = 0; mi < 4; mi++) {
    int m = m0 + wrow * 64 + mi * 16 + crow0;
#pragma unroll
    for (int ni = 0; ni < 4; ni++) {
      int nn = n0 + wcol * 64 + ni * 16 + ccol;
      float* cp = Cz + (size_t)m * CO + nn;
#pragma unroll
      for (int jj = 0; jj < 4; jj++) cp[(size_t)jj * CO] = acc[mi][ni][jj];
    }
  }
  if constexpr (SPLIT == 1) {
    // fused BN partials: per-thread 16-row sums per owned column
    const int contrib = kg * 2 + wrow;  // 8 contributors per column
#pragma unroll
    for (int ni = 0; ni < 4; ni++) {
      float s = 0.f, q = 0.f;
#pragma unroll
      for (int mi = 0; mi < 4; mi++)
#pragma unroll
        for (int jj = 0; jj < 4; jj++) {
          float v = acc[mi][ni][jj];
          s += v; q += v * v;
        }
      int coll = wcol * 64 + ni * 16 + ccol;
      red[0][coll][contrib] = s;
      red[1][coll][contrib] = q;
    }
    __syncthreads();
    if (t < 128) {
      float s = 0.f, q = 0.f;
#pragma unroll
      for (int j = 0; j < 8; j++) { s += red[0][t][j]; q += red[1][t][j]; }
      size_t c = n0 + t;
      part[(c * gridDim.x + blockIdx.x) * 2 + 0] = s;
      part[(c * gridDim.x + blockIdx.x) * 2 + 1] = q;
    }
  }
}

// ---------------- split-K reduction + BN partials ----------------
template<int M, int CO, int SPLIT, int NS>
__global__ __launch_bounds__(256) void reduce_bn_k(const float* __restrict__ Cp,
                                                   float* __restrict__ Cf,
                                                   float* __restrict__ part) {
  int c = blockIdx.x * 64 + (threadIdx.x & 63);
  int rl = threadIdx.x >> 6;
  constexpr int ROWS = M / NS;
  int r0 = blockIdx.y * ROWS;
  float sum = 0.f, sq = 0.f;
  for (int r = r0 + rl; r < r0 + ROWS; r += 4) {
    float v = 0.f;
#pragma unroll
    for (int s = 0; s < SPLIT; s++) v += Cp[(size_t)s * M * CO + (size_t)r * CO + c];
    Cf[(size_t)r * CO + c] = v;
    sum += v; sq += v * v;
  }
  __shared__ float ls[256], lq[256];
  ls[threadIdx.x] = sum; lq[threadIdx.x] = sq;
  __syncthreads();
  if (threadIdx.x < 64) {
    sum = ls[threadIdx.x] + ls[threadIdx.x + 64] + ls[threadIdx.x + 128] + ls[threadIdx.x + 192];
    sq  = lq[threadIdx.x] + lq[threadIdx.x + 64] + lq[threadIdx.x + 128] + lq[threadIdx.x + 192];
    part[((size_t)c * NS + blockIdx.y) * 2 + 0] = sum;
    part[((size_t)c * NS + blockIdx.y) * 2 + 1] = sq;
  }
}

__global__ void bn_finalize(const float* __restrict__ part,
                            const float* __restrict__ g, const float* __restrict__ b,
                            float* __restrict__ scale, float* __restrict__ shift,
                            int C, int S, float invCount) {
  int c = blockIdx.x * blockDim.x + threadIdx.x;
  if (c >= C) return;
  float sum = 0.f, sq = 0.f;
  for (int s = 0; s < S; s++) { sum += part[((size_t)c * S + s) * 2]; sq += part[((size_t)c * S + s) * 2 + 1]; }
  float m = sum * invCount;
  float var = sq * invCount - m * m;
  float sc = g[c] * rsqrtf(var + 1e-5f);
  scale[c] = sc;
  shift[c] = b[c] - m * sc;
}

// ---------------- fused BN + ReLU (+2x2 pool) + pad, fp32 -> hi/lo ---------
// Index space covers the PADDED output; halo lanes write zeros (no memset).
template<int CO, int IH, int IW, bool POOL, int PADO>
__global__ __launch_bounds__(256) void bn_act_pad_k(const float* __restrict__ x,
                                                    const float* __restrict__ scale,
                                                    const float* __restrict__ shift,
                                                    bf16* __restrict__ yh,
                                                    bf16* __restrict__ yl) {
  constexpr int OH2 = POOL ? IH / 2 : IH, OW2 = POOL ? IW / 2 : IW;
  constexpr int OHP = OH2 + 2 * PADO, OWP = OW2 + 2 * PADO;
  int i = blockIdx.x * 256 + threadIdx.x;
  if (i >= 64 * OHP * OWP * CO) return;
  int c = i % CO; int t = i / CO; int owp = t % OWP; t /= OWP; int ohp = t % OHP; int n = t / OHP;
  int oh = ohp - PADO, ow = owp - PADO;
  float v = 0.f;
  if (oh >= 0 && oh < OH2 && ow >= 0 && ow < OW2) {
    float sc = scale[c], sh = shift[c];
    if (POOL) {
      const float* p = x + (((size_t)(n * IH) + oh * 2) * IW + ow * 2) * CO + c;
      float a = p[0] * sc + sh;
      float b2 = p[CO] * sc + sh;
      float d = p[(size_t)IW * CO] * sc + sh;
      float e = p[(size_t)(IW + 1) * CO] * sc + sh;
      v = fmaxf(fmaxf(a, b2), fmaxf(d, e));
    } else {
      v = x[(((size_t)(n * OH2) + oh) * OW2 + ow) * CO + c] * sc + sh;
    }
    v = fmaxf(v, 0.f);
  }
  bf16 h, l; split2(v, h, l);
  yh[i] = h; yl[i] = l;
}

// ---------------- ROI SPP: feat hi/lo [64][6][16][512] -> S hi/lo ----------
__global__ __launch_bounds__(256) void spp_k(const bf16* __restrict__ fh,
                                             const bf16* __restrict__ fl,
                                             const int* __restrict__ roi,
                                             bf16* __restrict__ oh_,
                                             bf16* __restrict__ ol_) {
  int c = blockIdx.x * 256 + threadIdx.x;  // 0..511
  int r = blockIdx.y;                      // 0..255
  const int* rp = roi + r * 5;
  int im = rp[0];
  int c1 = rp[1] >> 3, r1 = rp[2] >> 3, c2 = rp[3] >> 3, r2 = rp[4] >> 3;
  int w = c2 - c1 + 1;
  int lo[6], hi[6];
  int bi = 0;
#pragma unroll
  for (int l = 1; l <= 3; l++)
    for (int k = 0; k < l; k++) {
      lo[bi] = c1 + (k * w) / l;
      hi[bi] = c1 + ((k + 1) * w + l - 1) / l - 1;
      bi++;
    }
  float mx[6];
#pragma unroll
  for (int b = 0; b < 6; b++) mx[b] = -1e30f;
  const bf16* ph = fh + (size_t)im * 96 * 512 + c;
  const bf16* pl = fl + (size_t)im * 96 * 512 + c;
  for (int row = r1; row <= r2; row++)
    for (int col = c1; col <= c2; col++) {
      size_t off = (size_t)(row * 16 + col) * 512;
      float v = (float)ph[off] + (float)pl[off];
#pragma unroll
      for (int b = 0; b < 6; b++)
        if (col >= lo[b] && col <= hi[b]) mx[b] = fmaxf(mx[b], v);
    }
  int idx[6] = {c, 512 + c * 2, 512 + c * 2 + 1, 1536 + c * 3, 1536 + c * 3 + 1, 1536 + c * 3 + 2};
#pragma unroll
  for (int b = 0; b < 6; b++) {
    bf16 h, l; split2(mx[b], h, l);
    oh_[(size_t)r * 3072 + idx[b]] = h;
    ol_[(size_t)r * 3072 + idx[b]] = l;
  }
}

// FC1: BN+ReLU, write hi/lo into CC[:, 0:2048] (ld 8192)
__global__ __launch_bounds__(256) void bn1d_apply_cc_k(const float* __restrict__ x,
                                                       const float* __restrict__ scale,
                                                       const float* __restrict__ shift,
                                                       bf16* __restrict__ ch,
                                                       bf16* __restrict__ cl) {
  int i = blockIdx.x * 256 + threadIdx.x;
  if (i >= 256 * 2048) return;
  int f = i & 2047, r = i >> 11;
  float v = fmaxf(x[i] * scale[f] + shift[f], 0.f);
  bf16 h, l; split2(v, h, l);
  ch[(size_t)r * 8192 + f] = h;
  cl[(size_t)r * 8192 + f] = l;
}

// FC2: BN+ReLU, fp32 out
__global__ __launch_bounds__(256) void bn1d_apply_f32_k(const float* __restrict__ x,
                                                        const float* __restrict__ scale,
                                                        const float* __restrict__ shift,
                                                        float* __restrict__ y) {
  int i = blockIdx.x * 256 + threadIdx.x;
  if (i >= 256 * 2048) return;
  int f = i & 2047;
  y[i] = fmaxf(x[i] * scale[f] + shift[f], 0.f);
}

// ---------------- weight transforms ----------------
template<int CI, int CO, int KS>
__global__ __launch_bounds__(256) void wconv_k(const float* __restrict__ w,
                                               bf16* __restrict__ oh_,
                                               bf16* __restrict__ ol_) {
  int i = blockIdx.x * 256 + threadIdx.x;
  if (i >= CO * KS * KS * CI) return;
  int ci = i % CI; int t = i / CI; int kw = t % KS; t /= KS; int kh = t % KS; int co = t / KS;
  float v = w[(((size_t)co * CI + ci) * KS + kh) * KS + kw];
  bf16 h, l; split2(v, h, l);
  oh_[i] = h; ol_[i] = l;
}

__global__ __launch_bounds__(256) void cast_k(const float* __restrict__ x,
                                              bf16* __restrict__ y, int n) {
  int i = blockIdx.x * 256 + threadIdx.x;
  if (i < n) y[i] = (bf16)x[i];
}

// f2w [2048][7901] fp32 -> [2048][8192] bf16 hi (zero tail)
__global__ __launch_bounds__(256) void wfc2_k(const float* __restrict__ x,
                                              bf16* __restrict__ y) {
  int i = blockIdx.x * 256 + threadIdx.x;
  if (i >= 2048 * 8192) return;
  int k = i & 8191, n = i >> 13;
  y[i] = (bf16)(k < 7901 ? x[(size_t)n * 7901 + k] : 0.f);
}

// phoc [256][5853] fp32 -> CC[:, 2048:8192] hi/lo (zero tail cols)
__global__ __launch_bounds__(256) void phoc_cc_k(const float* __restrict__ phoc,
                                                 bf16* __restrict__ ch,
                                                 bf16* __restrict__ cl) {
  int i = blockIdx.x * 256 + threadIdx.x;
  if (i >= 256 * 6144) return;
  int k = i % 6144, r = i / 6144;
  int col = 2048 + k;
  float v = (col < 7901) ? phoc[(size_t)r * 5853 + (col - 2048)] : 0.f;
  bf16 h, l; split2(v, h, l);
  ch[(size_t)r * 8192 + col] = h;
  cl[(size_t)r * 8192 + col] = l;
}

// ============================================================================
extern "C" void kernel_launch(void* const* d_in, const int* in_sizes, int n_in,
                              void* d_out, int out_size, void* d_ws, size_t ws_size,
                              hipStream_t stream) {
  (void)in_sizes; (void)n_in; (void)out_size; (void)ws_size;

  const float* x    = (const float*)d_in[0];
  const int*   roi  = (const int*)  d_in[1];
  const float* phoc = (const float*)d_in[2];
  const float* c1w  = (const float*)d_in[3];
  const float* g1   = (const float*)d_in[5];
  const float* b1   = (const float*)d_in[6];
  const float* c2w  = (const float*)d_in[7];
  const float* g2   = (const float*)d_in[9];
  const float* b2   = (const float*)d_in[10];
  const float* c3w  = (const float*)d_in[11];
  const float* g3   = (const float*)d_in[13];
  const float* b3   = (const float*)d_in[14];
  const float* c4w  = (const float*)d_in[15];
  const float* g4   = (const float*)d_in[17];
  const float* b4   = (const float*)d_in[18];
  const float* c5w  = (const float*)d_in[19];
  const float* g5   = (const float*)d_in[21];
  const float* b5   = (const float*)d_in[22];
  const float* f1w  = (const float*)d_in[23];
  const float* g6   = (const float*)d_in[25];
  const float* b6   = (const float*)d_in[26];
  const float* f2w  = (const float*)d_in[27];
  const float* g7   = (const float*)d_in[29];
  const float* b7   = (const float*)d_in[30];
  float* out = (float*)d_out;

  // ---- workspace layout (total ~168.4 MB) ----
  char* ws = (char*)d_ws;
  float* P    = (float*)(ws + 0x0000000);   // 1.76 MB
  bf16*  Ahi  = (bf16*) (ws + 0x0200000);   // 16 MB
  bf16*  Alo  = (bf16*) (ws + 0x1200000);   // 16 MB
  float* C    = (float*)(ws + 0x2200000);   // 51 MB region (GEMM out / split slabs)
  float* C5F  = (float*)(ws + 0x4200000);   // conv5 final (32MB into C region)
  bf16*  Wc2h = (bf16*) (ws + 0x5500000);
  bf16*  Wc3h = (bf16*) (ws + 0x5570000);
  bf16*  Wc4h = (bf16*) (ws + 0x5600000);
  bf16*  Wc5h = (bf16*) (ws + 0x5840000);
  bf16*  Wf1  = (bf16*) (ws + 0x5CC0000);
  bf16*  Wf2  = (bf16*) (ws + 0x68C0000);   // [2048][8192] = 32 MB
  bf16*  Wc2l = (bf16*) (ws + 0x88C0000);
  bf16*  Wc3l = (bf16*) (ws + 0x8930000);
  bf16*  Wc4l = (bf16*) (ws + 0x89C0000);
  bf16*  Wc5l = (bf16*) (ws + 0x8C00000);
  bf16*  Shi  = (bf16*) (ws + 0x9080000);   // spp out hi [256][3072]
  bf16*  Slo  = (bf16*) (ws + 0x9200000);
  float* G6   = (float*)(ws + 0x9380000);   // fc1 out fp32 [256][2048]
  bf16*  CChi = (bf16*) (ws + 0x9580000);   // concat hi [256][8192] = 4 MB
  bf16*  CClo = (bf16*) (ws + 0x9980000);
  float* G7   = (float*)(ws + 0x9D80000);   // fc2 out fp32 [256][2048]
  float* PART = (float*)(ws + 0x9F80000);   // 768 KB
  float* SC   = (float*)(ws + 0xA040000);
  float* SH   = (float*)(ws + 0xA050000);

  // ---- weight transforms ----
  wconv_k<64, 128, 5><<<800, 256, 0, stream>>>(c2w, Wc2h, Wc2l);
  wconv_k<128, 256, 3><<<1152, 256, 0, stream>>>(c3w, Wc3h, Wc3l);
  wconv_k<256, 512, 3><<<4608, 256, 0, stream>>>(c4w, Wc4h, Wc4l);
  wconv_k<512, 512, 3><<<9216, 256, 0, stream>>>(c5w, Wc5h, Wc5l);
  cast_k<<<24576, 256, 0, stream>>>(f1w, Wf1, 2048 * 3072);
  wfc2_k<<<65536, 256, 0, stream>>>(f2w, Wf2);
  phoc_cc_k<<<6144, 256, 0, stream>>>(phoc, CChi, CClo);

  // ---- conv1 (two-pass, no big fp32 buffer) ----
  pad_edge_k<<<1716, 256, 0, stream>>>(x, P);
  conv1_stats_k<<<dim3(96, 8), 256, 0, stream>>>(P, c1w, PART);
  bn_finalize<<<1, 64, 0, stream>>>(PART, g1, b1, SC, SH, 64, 96, 1.f / 393216.f);
  hipMemsetAsync(Ahi, 0, (size_t)64 * 28 * 68 * 64 * 2, stream);
  hipMemsetAsync(Alo, 0, (size_t)64 * 28 * 68 * 64 * 2, stream);
  conv1_apply_k<<<dim3(384, 8), 256, 0, stream>>>(P, c1w, SC, SH, Ahi, Alo);

  // ---- conv2 (2-pass): A[98304][1600] -> C[98304][128] ----
  conv_gemm_k<64, 5, 24, 64, 128, false, 1><<<dim3(768, 1), 256, 0, stream>>>(Ahi, Alo, Wc2h, nullptr, C, PART);
  bn_finalize<<<1, 128, 0, stream>>>(PART, g2, b2, SC, SH, 128, 768, 1.f / 98304.f);
  bn_act_pad_k<128, 24, 64, true, 1><<<15232, 256, 0, stream>>>(C, SC, SH, Ahi, Alo);

  // ---- conv3 (3-pass) ----
  conv_gemm_k<128, 3, 12, 32, 256, true, 1><<<dim3(192, 2), 256, 0, stream>>>(Ahi, Alo, Wc3h, Wc3l, C, PART);
  bn_finalize<<<1, 256, 0, stream>>>(PART, g3, b3, SC, SH, 256, 192, 1.f / 24576.f);
  bn_act_pad_k<256, 12, 32, false, 1><<<30464, 256, 0, stream>>>(C, SC, SH, Ahi, Alo);

  // ---- conv4 (2-pass) ----
  conv_gemm_k<256, 3, 12, 32, 512, false, 1><<<dim3(192, 4), 256, 0, stream>>>(Ahi, Alo, Wc4h, nullptr, C, PART);
  bn_finalize<<<2, 256, 0, stream>>>(PART, g4, b4, SC, SH, 512, 192, 1.f / 24576.f);
  bn_act_pad_k<512, 12, 32, true, 1><<<18432, 256, 0, stream>>>(C, SC, SH, Ahi, Alo);

  // ---- conv5 (3-pass, split-K=2): partial slabs in C, final in C5F ----
  conv_gemm_k<512, 3, 6, 16, 512, true, 2><<<dim3(48, 4, 2), 256, 0, stream>>>(Ahi, Alo, Wc5h, Wc5l, C, nullptr);
  reduce_bn_k<6144, 512, 2, 16><<<dim3(8, 16), 256, 0, stream>>>(C, C5F, PART);
  bn_finalize<<<2, 256, 0, stream>>>(PART, g5, b5, SC, SH, 512, 16, 1.f / 6144.f);
  bn_act_pad_k<512, 6, 16, false, 0><<<12288, 256, 0, stream>>>(C5F, SC, SH, Ahi, Alo);  // feat

  // ---- SPP ----
  spp_k<<<dim3(2, 256), 256, 0, stream>>>(Ahi, Alo, roi, Shi, Slo);

  // ---- FC1 (split-K=8): [256][3072] x [2048][3072] ----
  conv_gemm_k<3072, 1, 2, 2, 2048, false, 8><<<dim3(2, 16, 8), 256, 0, stream>>>(Shi, Slo, Wf1, nullptr, C, nullptr);
  reduce_bn_k<256, 2048, 8, 4><<<dim3(32, 4), 256, 0, stream>>>(C, G6, PART);
  bn_finalize<<<8, 256, 0, stream>>>(PART, g6, b6, SC, SH, 2048, 4, 1.f / 256.f);
  bn1d_apply_cc_k<<<2048, 256, 0, stream>>>(G6, SC, SH, CChi, CClo);

  // ---- FC2 (split-K=8): [256][8192] x [2048][8192] ----
  conv_gemm_k<8192, 1, 2, 2, 2048, false, 8><<<dim3(2, 16, 8), 256, 0, stream>>>(CChi, CClo, Wf2, nullptr, C, nullptr);
  reduce_bn_k<256, 2048, 8, 4><<<dim3(32, 4), 256, 0, stream>>>(C, G7, PART);
  bn_finalize<<<8, 256, 0, stream>>>(PART, g7, b7, SC, SH, 2048, 4, 1.f / 256.f);
  bn1d_apply_f32_k<<<2048, 256, 0, stream>>>(G7, SC, SH, out);
}

// Round 7
// 745.075 us; speedup vs baseline: 10.5964x; 1.1010x over previous
//
#include <hip/hip_runtime.h>
#include <hip/hip_bf16.h>

// ============================================================================
// HWNet-SPP forward, MFMA bf16 implicit-GEMM with selective hi/lo precision.
// Pass config per layer (error budget vs absmax threshold 0.098):
//   conv2: Ah*Bh                (1-pass)   conv3: Ah*Bh + Al*Bh  (2-pass)
//   conv4: Ah*Bh                (1-pass)   conv5: full 3-pass hi/lo
//   FC1/FC2: Ah*Bh + Al*Bh      (2-pass)
// BN column stats fused into GEMM epilogue (SPLIT==1) or split-K reducer.
// Conv/FC biases skipped (BN mean-subtraction cancels them exactly).
// ============================================================================

typedef __bf16 bf16;
using bf16x8 = __attribute__((ext_vector_type(8))) __bf16;
using f32x4  = __attribute__((ext_vector_type(4))) float;

__device__ __forceinline__ void split2(float v, bf16& h, bf16& l) {
  bf16 hb = (bf16)v;
  h = hb;
  l = (bf16)(v - (float)hb);
}

__device__ __forceinline__ void gld_lds16(const bf16* g, void* lds) {
  __builtin_amdgcn_global_load_lds(
      (const __attribute__((address_space(1))) unsigned int*)g,
      (__attribute__((address_space(3))) unsigned int*)lds, 16, 0, 0);
}

// ---------------- pad (edge mode, +2 each side of 48x128) ----------------
__global__ __launch_bounds__(256) void pad_edge_k(const float* __restrict__ x,
                                                  float* __restrict__ p) {
  int i = blockIdx.x * 256 + threadIdx.x;
  const int TOT = 64 * 52 * 132;
  if (i >= TOT) return;
  int w = i % 132; int t = i / 132; int h = t % 52; int n = t / 52;
  int sh = h - 2; sh = sh < 0 ? 0 : (sh > 47 ? 47 : sh);
  int sw = w - 2; sw = sw < 0 ? 0 : (sw > 127 ? 127 : sw);
  p[i] = x[(n * 48 + sh) * 128 + sw];
}

// ---------------- conv1 pass 1: BN stats only (fp32, recompute style) ------
__global__ __launch_bounds__(256) void conv1_stats_k(const float* __restrict__ P,
                                                     const float* __restrict__ wt,
                                                     float* __restrict__ part) {
  int co0 = blockIdx.y * 8;
  float sums[8] = {0.f}, sqs[8] = {0.f};
  for (int r = 0; r < 16; r++) {
    int pix = blockIdx.x * 4096 + r * 256 + threadIdx.x;  // 0..393215
    int w = pix & 127; int t = pix >> 7; int h = t % 48; int n = t / 48;
    const float* ip = P + ((size_t)n * 52 + h) * 132 + w;
    float win[25];
#pragma unroll
    for (int kh = 0; kh < 5; kh++)
#pragma unroll
      for (int kw = 0; kw < 5; kw++) win[kh * 5 + kw] = ip[kh * 132 + kw];
#pragma unroll
    for (int j = 0; j < 8; j++) {
      const float* wp = wt + (size_t)(co0 + j) * 25;
      float acc = 0.f;
#pragma unroll
      for (int k = 0; k < 25; k++) acc += win[k] * wp[k];
      sums[j] += acc; sqs[j] += acc * acc;
    }
  }
  __shared__ float ls[256], lq[256];
  for (int j = 0; j < 8; j++) {
    ls[threadIdx.x] = sums[j]; lq[threadIdx.x] = sqs[j];
    __syncthreads();
    for (int o = 128; o > 0; o >>= 1) {
      if (threadIdx.x < o) { ls[threadIdx.x] += ls[threadIdx.x + o]; lq[threadIdx.x] += lq[threadIdx.x + o]; }
      __syncthreads();
    }
    if (threadIdx.x == 0) {
      int c = co0 + j;
      part[((size_t)c * 96 + blockIdx.x) * 2 + 0] = ls[0];
      part[((size_t)c * 96 + blockIdx.x) * 2 + 1] = lq[0];
    }
    __syncthreads();
  }
}

// ---------------- conv1 pass 2: conv+BN+ReLU+pool+pad -> hi/lo -------------
__global__ __launch_bounds__(256) void conv1_apply_k(const float* __restrict__ P,
                                                     const float* __restrict__ wt,
                                                     const float* __restrict__ scale,
                                                     const float* __restrict__ shift,
                                                     bf16* __restrict__ yh,
                                                     bf16* __restrict__ yl) {
  int pix = blockIdx.x * 256 + threadIdx.x;  // 0..98303
  int ow = pix & 63; int t = pix >> 6; int oh = t % 24; int n = t / 24;
  int co0 = blockIdx.y * 8;
  const float* ip = P + ((size_t)n * 52 + 2 * oh) * 132 + 2 * ow;
  float win[36];
#pragma unroll
  for (int r = 0; r < 6; r++)
#pragma unroll
    for (int c = 0; c < 6; c++) win[r * 6 + c] = ip[r * 132 + c];
  bf16x8 hv, lv;
#pragma unroll
  for (int j = 0; j < 8; j++) {
    const float* wp = wt + (size_t)(co0 + j) * 25;
    float sc = scale[co0 + j], sh = shift[co0 + j];
    float m = -1e30f;
#pragma unroll
    for (int dy = 0; dy < 2; dy++)
#pragma unroll
      for (int dx = 0; dx < 2; dx++) {
        float acc = 0.f;
#pragma unroll
        for (int kh = 0; kh < 5; kh++)
#pragma unroll
          for (int kw = 0; kw < 5; kw++)
            acc += win[(kh + dy) * 6 + kw + dx] * wp[kh * 5 + kw];
        m = fmaxf(m, acc * sc + sh);
      }
    float v = fmaxf(m, 0.f);
    bf16 h, l; split2(v, h, l);
    hv[j] = h; lv[j] = l;
  }
  size_t o = (((size_t)n * 28 + oh + 2) * 68 + ow + 2) * 64 + co0;
  *(bf16x8*)(yh + o) = hv;
  *(bf16x8*)(yl + o) = lv;
}

// ---------------- MFMA implicit-GEMM, selective hi/lo, optional split-K ----
// C[m,co] = Ah.Bh (+ Al.Bh if ALO) (+ Ah.Bl if BLO)
// A from padded NHWC bf16 [64][OH+KS-1][OW+KS-1][CI]; FC: KS=1,OH=OW=2.
// Tile 128x128, BK=64, 4 waves, st-swizzle via pre-swizzled source addrs.
template<int CI, int KS, int OH, int OW, int CO, bool ALO, bool BLO, int SPLIT>
__global__ __launch_bounds__(256) void conv_gemm_k(const bf16* __restrict__ Ahi,
                                                   const bf16* __restrict__ Alo,
                                                   const bf16* __restrict__ Bhi,
                                                   const bf16* __restrict__ Blo,
                                                   float* __restrict__ Cout,
                                                   float* __restrict__ part) {
  static_assert(CI % 64 == 0, "chunk must not straddle ci segments");
  constexpr int K = KS * KS * CI;
  constexpr int IWP = OW + KS - 1;
  constexpr int NCH = K / 64;
  static_assert(NCH % SPLIT == 0, "split must divide chunk count");
  constexpr int NCHS = NCH / SPLIT;
  constexpr int M = 64 * OH * OW;
  __shared__ bf16 Ash[128 * 64];
  __shared__ bf16 Asl[ALO ? 128 * 64 : 64];
  __shared__ bf16 Bsh[128 * 64];
  __shared__ bf16 Bsl[BLO ? 128 * 64 : 64];
  __shared__ float red[2][128][8];
  const int t = threadIdx.x;
  const int lane = t & 63, w = t >> 6;
  const int m0 = blockIdx.x * 128, n0 = blockIdx.y * 128;
  const int z = (SPLIT > 1) ? blockIdx.z : 0;

  // staging source precompute: issue i covers rows (i*4+w)*8 .. +8
  int apix[4]; size_t boff[4];
#pragma unroll
  for (int i = 0; i < 4; i++) {
    int f = (i * 4 + w) * 64 + lane;
    int row = f >> 3, slot = f & 7;
    int ss = slot ^ (row & 7);               // st-swizzle on source
    int m = m0 + row;
    int n = m / (OH * OW); int rem = m % (OH * OW);
    int oh = rem / OW, ow_ = rem % OW;
    apix[i] = ((n * (OH + KS - 1) + oh) * IWP + ow_) * CI + ss * 8;
    boff[i] = (size_t)(n0 + row) * K + ss * 8;
  }

  // ds_read fragment addresses
  const int wrow = w >> 1, wcol = w & 1;
  const int kg = lane >> 4;
  int arb[4], amk[4], brb[4], bmk[4];
#pragma unroll
  for (int q = 0; q < 4; q++) {
    int ra = wrow * 64 + q * 16 + (lane & 15);
    arb[q] = ra * 128; amk[q] = ra & 7;
    int rb = wcol * 64 + q * 16 + (lane & 15);
    brb[q] = rb * 128; bmk[q] = rb & 7;
  }
  const char* Ashb = (const char*)Ash;
  const char* Aslb = (const char*)Asl;
  const char* Bshb = (const char*)Bsh;
  const char* Bslb = (const char*)Bsl;

  f32x4 acc[4][4] = {};
  for (int kc = z * NCHS; kc < (z + 1) * NCHS; ++kc) {
    const int k0 = kc * 64;
    const int seg = k0 / CI;
    const int ci0 = k0 % CI;
    const int kh = seg / KS, kw = seg % KS;
    const int aoff = (kh * IWP + kw) * CI + ci0;   // wave-uniform
#pragma unroll
    for (int i = 0; i < 4; i++) {
      gld_lds16(Ahi + (size_t)apix[i] + aoff, (char*)Ash + (i * 4 + w) * 1024);
      if (ALO)
        gld_lds16(Alo + (size_t)apix[i] + aoff, (char*)Asl + (i * 4 + w) * 1024);
      gld_lds16(Bhi + boff[i] + k0,           (char*)Bsh + (i * 4 + w) * 1024);
      if (BLO)
        gld_lds16(Blo + boff[i] + k0,         (char*)Bsl + (i * 4 + w) * 1024);
    }
    __syncthreads();
#pragma unroll
    for (int ks = 0; ks < 2; ks++) {
      const int slot = ks * 4 + kg;
      bf16x8 ah[4], bh[4];
#pragma unroll
      for (int q = 0; q < 4; q++) {
        ah[q] = *(const bf16x8*)(Ashb + arb[q] + ((slot ^ amk[q]) << 4));
        bh[q] = *(const bf16x8*)(Bshb + brb[q] + ((slot ^ bmk[q]) << 4));
      }
#pragma unroll
      for (int mi = 0; mi < 4; mi++)
#pragma unroll
        for (int ni = 0; ni < 4; ni++)
          acc[mi][ni] = __builtin_amdgcn_mfma_f32_16x16x32_bf16(ah[mi], bh[ni], acc[mi][ni], 0, 0, 0);
      if (ALO) {
        bf16x8 al[4];
#pragma unroll
        for (int q = 0; q < 4; q++)
          al[q] = *(const bf16x8*)(Aslb + arb[q] + ((slot ^ amk[q]) << 4));
#pragma unroll
        for (int mi = 0; mi < 4; mi++)
#pragma unroll
          for (int ni = 0; ni < 4; ni++)
            acc[mi][ni] = __builtin_amdgcn_mfma_f32_16x16x32_bf16(al[mi], bh[ni], acc[mi][ni], 0, 0, 0);
      }
      if (BLO) {
        bf16x8 bl[4];
#pragma unroll
        for (int q = 0; q < 4; q++)
          bl[q] = *(const bf16x8*)(Bslb + brb[q] + ((slot ^ bmk[q]) << 4));
#pragma unroll
        for (int mi = 0; mi < 4; mi++)
#pragma unroll
          for (int ni = 0; ni < 4; ni++)
            acc[mi][ni] = __builtin_amdgcn_mfma_f32_16x16x32_bf16(ah[mi], bl[ni], acc[mi][ni], 0, 0, 0);
      }
    }
    __syncthreads();
  }

  // epilogue: D row = (lane>>4)*4 + jj, col = lane&15
  const int crow0 = (lane >> 4) * 4, ccol = lane & 15;
  float* Cz = Cout + (size_t)z * M * CO;
#pragma unroll
  for (int mi = 0; mi < 4; mi++) {
    int m = m0 + wrow * 64 + mi * 16 + crow0;
#pragma unroll
    for (int ni = 0; ni < 4; ni++) {
      int nn = n0 + wcol * 64 + ni * 16 + ccol;
      float* cp = Cz + (size_t)m * CO + nn;
#pragma unroll
      for (int jj = 0; jj < 4; jj++) cp[(size_t)jj * CO] = acc[mi][ni][jj];
    }
  }
  if constexpr (SPLIT == 1) {
    // fused BN partials: per-thread 16-row sums per owned column
    const int contrib = kg * 2 + wrow;  // 8 contributors per column
#pragma unroll
    for (int ni = 0; ni < 4; ni++) {
      float s = 0.f, q = 0.f;
#pragma unroll
      for (int mi = 0; mi < 4; mi++)
#pragma unroll
        for (int jj = 0; jj < 4; jj++) {
          float v = acc[mi][ni][jj];
          s += v; q += v * v;
        }
      int coll = wcol * 64 + ni * 16 + ccol;
      red[0][coll][contrib] = s;
      red[1][coll][contrib] = q;
    }
    __syncthreads();
    if (t < 128) {
      float s = 0.f, q = 0.f;
#pragma unroll
      for (int j = 0; j < 8; j++) { s += red[0][t][j]; q += red[1][t][j]; }
      size_t c = n0 + t;
      part[(c * gridDim.x + blockIdx.x) * 2 + 0] = s;
      part[(c * gridDim.x + blockIdx.x) * 2 + 1] = q;
    }
  }
}

// ---------------- split-K reduction + BN partials ----------------
template<int M, int CO, int SPLIT, int NS>
__global__ __launch_bounds__(256) void reduce_bn_k(const float* __restrict__ Cp,
                                                   float* __restrict__ Cf,
                                                   float* __restrict__ part) {
  int c = blockIdx.x * 64 + (threadIdx.x & 63);
  int rl = threadIdx.x >> 6;
  constexpr int ROWS = M / NS;
  int r0 = blockIdx.y * ROWS;
  float sum = 0.f, sq = 0.f;
  for (int r = r0 + rl; r < r0 + ROWS; r += 4) {
    float v = 0.f;
#pragma unroll
    for (int s = 0; s < SPLIT; s++) v += Cp[(size_t)s * M * CO + (size_t)r * CO + c];
    Cf[(size_t)r * CO + c] = v;
    sum += v; sq += v * v;
  }
  __shared__ float ls[256], lq[256];
  ls[threadIdx.x] = sum; lq[threadIdx.x] = sq;
  __syncthreads();
  if (threadIdx.x < 64) {
    sum = ls[threadIdx.x] + ls[threadIdx.x + 64] + ls[threadIdx.x + 128] + ls[threadIdx.x + 192];
    sq  = lq[threadIdx.x] + lq[threadIdx.x + 64] + lq[threadIdx.x + 128] + lq[threadIdx.x + 192];
    part[((size_t)c * NS + blockIdx.y) * 2 + 0] = sum;
    part[((size_t)c * NS + blockIdx.y) * 2 + 1] = sq;
  }
}

__global__ void bn_finalize(const float* __restrict__ part,
                            const float* __restrict__ g, const float* __restrict__ b,
                            float* __restrict__ scale, float* __restrict__ shift,
                            int C, int S, float invCount) {
  int c = blockIdx.x * blockDim.x + threadIdx.x;
  if (c >= C) return;
  float sum = 0.f, sq = 0.f;
  for (int s = 0; s < S; s++) { sum += part[((size_t)c * S + s) * 2]; sq += part[((size_t)c * S + s) * 2 + 1]; }
  float m = sum * invCount;
  float var = sq * invCount - m * m;
  float sc = g[c] * rsqrtf(var + 1e-5f);
  scale[c] = sc;
  shift[c] = b[c] - m * sc;
}

// ---------------- fused BN + ReLU (+2x2 pool) + pad, fp32 -> hi/lo ---------
// Index space covers the PADDED output; halo lanes write zeros (no memset).
template<int CO, int IH, int IW, bool POOL, int PADO>
__global__ __launch_bounds__(256) void bn_act_pad_k(const float* __restrict__ x,
                                                    const float* __restrict__ scale,
                                                    const float* __restrict__ shift,
                                                    bf16* __restrict__ yh,
                                                    bf16* __restrict__ yl) {
  constexpr int OH2 = POOL ? IH / 2 : IH, OW2 = POOL ? IW / 2 : IW;
  constexpr int OHP = OH2 + 2 * PADO, OWP = OW2 + 2 * PADO;
  int i = blockIdx.x * 256 + threadIdx.x;
  if (i >= 64 * OHP * OWP * CO) return;
  int c = i % CO; int t = i / CO; int owp = t % OWP; t /= OWP; int ohp = t % OHP; int n = t / OHP;
  int oh = ohp - PADO, ow = owp - PADO;
  float v = 0.f;
  if (oh >= 0 && oh < OH2 && ow >= 0 && ow < OW2) {
    float sc = scale[c], sh = shift[c];
    if (POOL) {
      const float* p = x + (((size_t)(n * IH) + oh * 2) * IW + ow * 2) * CO + c;
      float a = p[0] * sc + sh;
      float b2 = p[CO] * sc + sh;
      float d = p[(size_t)IW * CO] * sc + sh;
      float e = p[(size_t)(IW + 1) * CO] * sc + sh;
      v = fmaxf(fmaxf(a, b2), fmaxf(d, e));
    } else {
      v = x[(((size_t)(n * OH2) + oh) * OW2 + ow) * CO + c] * sc + sh;
    }
    v = fmaxf(v, 0.f);
  }
  bf16 h, l; split2(v, h, l);
  yh[i] = h; yl[i] = l;
}

// ---------------- ROI SPP: feat hi/lo [64][6][16][512] -> S hi/lo ----------
__global__ __launch_bounds__(256) void spp_k(const bf16* __restrict__ fh,
                                             const bf16* __restrict__ fl,
                                             const int* __restrict__ roi,
                                             bf16* __restrict__ oh_,
                                             bf16* __restrict__ ol_) {
  int c = blockIdx.x * 256 + threadIdx.x;  // 0..511
  int r = blockIdx.y;                      // 0..255
  const int* rp = roi + r * 5;
  int im = rp[0];
  int c1 = rp[1] >> 3, r1 = rp[2] >> 3, c2 = rp[3] >> 3, r2 = rp[4] >> 3;
  int w = c2 - c1 + 1;
  int lo[6], hi[6];
  int bi = 0;
#pragma unroll
  for (int l = 1; l <= 3; l++)
    for (int k = 0; k < l; k++) {
      lo[bi] = c1 + (k * w) / l;
      hi[bi] = c1 + ((k + 1) * w + l - 1) / l - 1;
      bi++;
    }
  float mx[6];
#pragma unroll
  for (int b = 0; b < 6; b++) mx[b] = -1e30f;
  const bf16* ph = fh + (size_t)im * 96 * 512 + c;
  const bf16* pl = fl + (size_t)im * 96 * 512 + c;
  for (int row = r1; row <= r2; row++)
    for (int col = c1; col <= c2; col++) {
      size_t off = (size_t)(row * 16 + col) * 512;
      float v = (float)ph[off] + (float)pl[off];
#pragma unroll
      for (int b = 0; b < 6; b++)
        if (col >= lo[b] && col <= hi[b]) mx[b] = fmaxf(mx[b], v);
    }
  int idx[6] = {c, 512 + c * 2, 512 + c * 2 + 1, 1536 + c * 3, 1536 + c * 3 + 1, 1536 + c * 3 + 2};
#pragma unroll
  for (int b = 0; b < 6; b++) {
    bf16 h, l; split2(mx[b], h, l);
    oh_[(size_t)r * 3072 + idx[b]] = h;
    ol_[(size_t)r * 3072 + idx[b]] = l;
  }
}

// FC1: BN+ReLU, write hi/lo into CC[:, 0:2048] (ld 8192)
__global__ __launch_bounds__(256) void bn1d_apply_cc_k(const float* __restrict__ x,
                                                       const float* __restrict__ scale,
                                                       const float* __restrict__ shift,
                                                       bf16* __restrict__ ch,
                                                       bf16* __restrict__ cl) {
  int i = blockIdx.x * 256 + threadIdx.x;
  if (i >= 256 * 2048) return;
  int f = i & 2047, r = i >> 11;
  float v = fmaxf(x[i] * scale[f] + shift[f], 0.f);
  bf16 h, l; split2(v, h, l);
  ch[(size_t)r * 8192 + f] = h;
  cl[(size_t)r * 8192 + f] = l;
}

// FC2: BN+ReLU, fp32 out
__global__ __launch_bounds__(256) void bn1d_apply_f32_k(const float* __restrict__ x,
                                                        const float* __restrict__ scale,
                                                        const float* __restrict__ shift,
                                                        float* __restrict__ y) {
  int i = blockIdx.x * 256 + threadIdx.x;
  if (i >= 256 * 2048) return;
  int f = i & 2047;
  y[i] = fmaxf(x[i] * scale[f] + shift[f], 0.f);
}

// ---------------- weight transforms ----------------
template<int CI, int CO, int KS>
__global__ __launch_bounds__(256) void wconv_k(const float* __restrict__ w,
                                               bf16* __restrict__ oh_,
                                               bf16* __restrict__ ol_) {
  int i = blockIdx.x * 256 + threadIdx.x;
  if (i >= CO * KS * KS * CI) return;
  int ci = i % CI; int t = i / CI; int kw = t % KS; t /= KS; int kh = t % KS; int co = t / KS;
  float v = w[(((size_t)co * CI + ci) * KS + kh) * KS + kw];
  bf16 h, l; split2(v, h, l);
  oh_[i] = h;
  if (ol_) ol_[i] = l;
}

__global__ __launch_bounds__(256) void cast_k(const float* __restrict__ x,
                                              bf16* __restrict__ y, int n) {
  int i = blockIdx.x * 256 + threadIdx.x;
  if (i < n) y[i] = (bf16)x[i];
}

// f2w [2048][7901] fp32 -> [2048][8192] bf16 hi (zero tail)
__global__ __launch_bounds__(256) void wfc2_k(const float* __restrict__ x,
                                              bf16* __restrict__ y) {
  int i = blockIdx.x * 256 + threadIdx.x;
  if (i >= 2048 * 8192) return;
  int k = i & 8191, n = i >> 13;
  y[i] = (bf16)(k < 7901 ? x[(size_t)n * 7901 + k] : 0.f);
}

// phoc [256][5853] fp32 -> CC[:, 2048:8192] hi/lo (zero tail cols)
__global__ __launch_bounds__(256) void phoc_cc_k(const float* __restrict__ phoc,
                                                 bf16* __restrict__ ch,
                                                 bf16* __restrict__ cl) {
  int i = blockIdx.x * 256 + threadIdx.x;
  if (i >= 256 * 6144) return;
  int k = i % 6144, r = i / 6144;
  int col = 2048 + k;
  float v = (col < 7901) ? phoc[(size_t)r * 5853 + (col - 2048)] : 0.f;
  bf16 h, l; split2(v, h, l);
  ch[(size_t)r * 8192 + col] = h;
  cl[(size_t)r * 8192 + col] = l;
}

// ============================================================================
extern "C" void kernel_launch(void* const* d_in, const int* in_sizes, int n_in,
                              void* d_out, int out_size, void* d_ws, size_t ws_size,
                              hipStream_t stream) {
  (void)in_sizes; (void)n_in; (void)out_size; (void)ws_size;

  const float* x    = (const float*)d_in[0];
  const int*   roi  = (const int*)  d_in[1];
  const float* phoc = (const float*)d_in[2];
  const float* c1w  = (const float*)d_in[3];
  const float* g1   = (const float*)d_in[5];
  const float* b1   = (const float*)d_in[6];
  const float* c2w  = (const float*)d_in[7];
  const float* g2   = (const float*)d_in[9];
  const float* b2   = (const float*)d_in[10];
  const float* c3w  = (const float*)d_in[11];
  const float* g3   = (const float*)d_in[13];
  const float* b3   = (const float*)d_in[14];
  const float* c4w  = (const float*)d_in[15];
  const float* g4   = (const float*)d_in[17];
  const float* b4   = (const float*)d_in[18];
  const float* c5w  = (const float*)d_in[19];
  const float* g5   = (const float*)d_in[21];
  const float* b5   = (const float*)d_in[22];
  const float* f1w  = (const float*)d_in[23];
  const float* g6   = (const float*)d_in[25];
  const float* b6   = (const float*)d_in[26];
  const float* f2w  = (const float*)d_in[27];
  const float* g7   = (const float*)d_in[29];
  const float* b7   = (const float*)d_in[30];
  float* out = (float*)d_out;

  // ---- workspace layout (total ~168.4 MB) ----
  char* ws = (char*)d_ws;
  float* P    = (float*)(ws + 0x0000000);   // 1.76 MB
  bf16*  Ahi  = (bf16*) (ws + 0x0200000);   // 16 MB
  bf16*  Alo  = (bf16*) (ws + 0x1200000);   // 16 MB
  float* C    = (float*)(ws + 0x2200000);   // 51 MB region (GEMM out / split slabs)
  float* C5F  = (float*)(ws + 0x4200000);   // conv5 final (32MB into C region)
  bf16*  Wc2h = (bf16*) (ws + 0x5500000);
  bf16*  Wc3h = (bf16*) (ws + 0x5570000);
  bf16*  Wc4h = (bf16*) (ws + 0x5600000);
  bf16*  Wc5h = (bf16*) (ws + 0x5840000);
  bf16*  Wf1  = (bf16*) (ws + 0x5CC0000);
  bf16*  Wf2  = (bf16*) (ws + 0x68C0000);   // [2048][8192] = 32 MB
  bf16*  Wc5l = (bf16*) (ws + 0x8C00000);
  bf16*  Shi  = (bf16*) (ws + 0x9080000);   // spp out hi [256][3072]
  bf16*  Slo  = (bf16*) (ws + 0x9200000);
  float* G6   = (float*)(ws + 0x9380000);   // fc1 out fp32 [256][2048]
  bf16*  CChi = (bf16*) (ws + 0x9580000);   // concat hi [256][8192] = 4 MB
  bf16*  CClo = (bf16*) (ws + 0x9980000);
  float* G7   = (float*)(ws + 0x9D80000);   // fc2 out fp32 [256][2048]
  float* PART = (float*)(ws + 0x9F80000);   // 768 KB
  float* SC   = (float*)(ws + 0xA040000);
  float* SH   = (float*)(ws + 0xA050000);

  // ---- weight transforms ----
  wconv_k<64, 128, 5><<<800, 256, 0, stream>>>(c2w, Wc2h, nullptr);
  wconv_k<128, 256, 3><<<1152, 256, 0, stream>>>(c3w, Wc3h, nullptr);
  wconv_k<256, 512, 3><<<4608, 256, 0, stream>>>(c4w, Wc4h, nullptr);
  wconv_k<512, 512, 3><<<9216, 256, 0, stream>>>(c5w, Wc5h, Wc5l);
  cast_k<<<24576, 256, 0, stream>>>(f1w, Wf1, 2048 * 3072);
  wfc2_k<<<65536, 256, 0, stream>>>(f2w, Wf2);
  phoc_cc_k<<<6144, 256, 0, stream>>>(phoc, CChi, CClo);

  // ---- conv1 (two-pass, no big fp32 buffer) ----
  pad_edge_k<<<1716, 256, 0, stream>>>(x, P);
  conv1_stats_k<<<dim3(96, 8), 256, 0, stream>>>(P, c1w, PART);
  bn_finalize<<<1, 64, 0, stream>>>(PART, g1, b1, SC, SH, 64, 96, 1.f / 393216.f);
  hipMemsetAsync(Ahi, 0, (size_t)64 * 28 * 68 * 64 * 2, stream);
  hipMemsetAsync(Alo, 0, (size_t)64 * 28 * 68 * 64 * 2, stream);
  conv1_apply_k<<<dim3(384, 8), 256, 0, stream>>>(P, c1w, SC, SH, Ahi, Alo);

  // ---- conv2 (1-pass): A[98304][1600] -> C[98304][128] ----
  conv_gemm_k<64, 5, 24, 64, 128, false, false, 1><<<dim3(768, 1), 256, 0, stream>>>(Ahi, Alo, Wc2h, nullptr, C, PART);
  bn_finalize<<<1, 128, 0, stream>>>(PART, g2, b2, SC, SH, 128, 768, 1.f / 98304.f);
  bn_act_pad_k<128, 24, 64, true, 1><<<15232, 256, 0, stream>>>(C, SC, SH, Ahi, Alo);

  // ---- conv3 (2-pass: Ah.Bh + Al.Bh) ----
  conv_gemm_k<128, 3, 12, 32, 256, true, false, 1><<<dim3(192, 2), 256, 0, stream>>>(Ahi, Alo, Wc3h, nullptr, C, PART);
  bn_finalize<<<1, 256, 0, stream>>>(PART, g3, b3, SC, SH, 256, 192, 1.f / 24576.f);
  bn_act_pad_k<256, 12, 32, false, 1><<<30464, 256, 0, stream>>>(C, SC, SH, Ahi, Alo);

  // ---- conv4 (1-pass) ----
  conv_gemm_k<256, 3, 12, 32, 512, false, false, 1><<<dim3(192, 4), 256, 0, stream>>>(Ahi, Alo, Wc4h, nullptr, C, PART);
  bn_finalize<<<2, 256, 0, stream>>>(PART, g4, b4, SC, SH, 512, 192, 1.f / 24576.f);
  bn_act_pad_k<512, 12, 32, true, 1><<<18432, 256, 0, stream>>>(C, SC, SH, Ahi, Alo);

  // ---- conv5 (3-pass, split-K=2): partial slabs in C, final in C5F ----
  conv_gemm_k<512, 3, 6, 16, 512, true, true, 2><<<dim3(48, 4, 2), 256, 0, stream>>>(Ahi, Alo, Wc5h, Wc5l, C, nullptr);
  reduce_bn_k<6144, 512, 2, 16><<<dim3(8, 16), 256, 0, stream>>>(C, C5F, PART);
  bn_finalize<<<2, 256, 0, stream>>>(PART, g5, b5, SC, SH, 512, 16, 1.f / 6144.f);
  bn_act_pad_k<512, 6, 16, false, 0><<<12288, 256, 0, stream>>>(C5F, SC, SH, Ahi, Alo);  // feat

  // ---- SPP ----
  spp_k<<<dim3(2, 256), 256, 0, stream>>>(Ahi, Alo, roi, Shi, Slo);

  // ---- FC1 (2-pass, split-K=8): [256][3072] x [2048][3072] ----
  conv_gemm_k<3072, 1, 2, 2, 2048, true, false, 8><<<dim3(2, 16, 8), 256, 0, stream>>>(Shi, Slo, Wf1, nullptr, C, nullptr);
  reduce_bn_k<256, 2048, 8, 4><<<dim3(32, 4), 256, 0, stream>>>(C, G6, PART);
  bn_finalize<<<8, 256, 0, stream>>>(PART, g6, b6, SC, SH, 2048, 4, 1.f / 256.f);
  bn1d_apply_cc_k<<<2048, 256, 0, stream>>>(G6, SC, SH, CChi, CClo);

  // ---- FC2 (2-pass, split-K=8): [256][8192] x [2048][8192] ----
  conv_gemm_k<8192, 1, 2, 2, 2048, true, false, 8><<<dim3(2, 16, 8), 256, 0, stream>>>(CChi, CClo, Wf2, nullptr, C, nullptr);
  reduce_bn_k<256, 2048, 8, 4><<<dim3(32, 4), 256, 0, stream>>>(C, G7, PART);
  bn_finalize<<<8, 256, 0, stream>>>(PART, g7, b7, SC, SH, 2048, 4, 1.f / 256.f);
  bn1d_apply_f32_k<<<2048, 256, 0, stream>>>(G7, SC, SH, out);
}